// Round 2
// baseline (4200.925 us; speedup 1.0000x reference)
//
#include <hip/hip_runtime.h>

#define NN 100000
#define NE 400000
#define DD 128
#define D3 384
#define KL 2
#define EPSBN 1e-5f
#define EB (NE/64)

typedef __attribute__((ext_vector_type(8))) short s16x8;
typedef __attribute__((ext_vector_type(4))) float f32x4;
typedef __attribute__((ext_vector_type(4))) unsigned short u16x4;

// stats block float offsets
#define ST_SUM    0      // [384] col sums (T,M,B)
#define ST_SQ     384    // [384]
#define ST_SCALE  768    // [384]
#define ST_SHIFT  1152   // [384]
#define ST_SUM1   1536
#define ST_SQ1    1537
#define ST_MAX    1538
#define ST_SEXP   1539
#define ST_SCALE1 1540
#define ST_SHIFT1 1541
#define ST_SUM2   1542   // [128]
#define ST_SQ2    1670   // [128]
#define ST_SCALE2 1798   // [128]
#define ST_SHIFT2 1926   // [128]
#define ST_TOTAL  2054

__device__ __forceinline__ float bf2f(unsigned short u){
  return __uint_as_float(((unsigned int)u) << 16);
}
__device__ __forceinline__ unsigned short f2bf(float f){
  unsigned int x = __float_as_uint(f);
  x = x + 0x7FFFu + ((x >> 16) & 1u);
  return (unsigned short)(x >> 16);
}

// ---------------- init: x -> d_out (f32 working copy) + bf16 copy ----------------
__global__ void init_x(const float* __restrict__ x, float* __restrict__ xcur,
                       unsigned short* __restrict__ xb){
  int stride = gridDim.x * blockDim.x;
  for (int i = blockIdx.x*blockDim.x + threadIdx.x; i < NN*DD; i += stride){
    float v = x[i];
    xcur[i] = v;
    xb[i] = f2bf(v);
  }
}

// ---------------- weight prep (per layer) ----------------
__global__ void wprep(const float* __restrict__ WT, const float* __restrict__ WM,
                      const float* __restrict__ WB, const float* __restrict__ Wtw,
                      unsigned short* __restrict__ Wcat, unsigned short* __restrict__ Wtwb){
  int stride = gridDim.x * blockDim.x;
  int tid = blockIdx.x*blockDim.x + threadIdx.x;
  for (int i = tid; i < 384*384; i += stride){
    int n = i / 384, k = i - n*384;
    float v;
    if (n < 128)      v = WT[n*384 + k];
    else if (n < 256) v = WM[(n-128)*384 + k];
    else              v = WB[(n-256)*384 + k];
    Wcat[i] = f2bf(v);
  }
  for (int i = tid; i < 128*128; i += stride) Wtwb[i] = f2bf(Wtw[i]);
}

// ---------------- CSR build ----------------
__global__ void csr_cnt(const int* __restrict__ twi, int* __restrict__ cnt){
  int e = blockIdx.x*blockDim.x + threadIdx.x;
  if (e < NE){
    atomicAdd(&cnt[0*NN + twi[0*NE + e]], 1);
    atomicAdd(&cnt[1*NN + twi[1*NE + e]], 1);
    atomicAdd(&cnt[2*NN + twi[2*NE + e]], 1);
  }
}

__global__ void csr_scan(const int* __restrict__ cnt, int* __restrict__ start){
  __shared__ int sums[1024];
  const int t = threadIdx.x;
  const int chunk = (NN + 1023) / 1024;
  for (int p = 0; p < 3; p++){
    const int* c = cnt + p*NN;
    int* s = start + p*NN;
    int lo = t*chunk, hi = lo + chunk; if (hi > NN) hi = NN; if (lo > NN) lo = NN;
    int acc = 0;
    for (int i = lo; i < hi; i++) acc += c[i];
    sums[t] = acc;
    __syncthreads();
    if (t == 0){
      int run = 0;
      for (int i = 0; i < 1024; i++){ int v = sums[i]; sums[i] = run; run += v; }
    }
    __syncthreads();
    int run = sums[t];
    for (int i = lo; i < hi; i++){ s[i] = run; run += c[i]; }
    __syncthreads();
  }
}

__global__ void csr_fill(const int* __restrict__ twi, const int* __restrict__ start,
                         int* __restrict__ cursor, int* __restrict__ lists){
  int e = blockIdx.x*blockDim.x + threadIdx.x;
  if (e < NE){
    #pragma unroll
    for (int p = 0; p < 3; p++){
      int n = twi[p*NE + e];
      int pos = atomicAdd(&cursor[p*NN + n], 1);
      lists[p*NE + start[p*NN + n] + pos] = e;
    }
  }
}

// ------------- gathered GEMM, one 128-col part per blockIdx.y / partArg -----------
// MODE 0: store bf16 h + BN col stats (Plan A)
// MODE 1: BN col stats only (Plan B pass 1)
// MODE 2: fused BN+ReLU+att/cnt epilogue, f32 atomic scatter into macc (Plan B p2)
template<int MODE>
__launch_bounds__(256)
__global__ void g1_gemm(const unsigned short* __restrict__ xb,
                        const unsigned short* __restrict__ Wcat,
                        const int* __restrict__ twi,
                        const int* __restrict__ cnt,
                        const float* __restrict__ spost,
                        unsigned short* __restrict__ h,
                        float* __restrict__ macc,
                        float* __restrict__ stats,
                        int partArg){
  __shared__ float lt[4][16][128];
  __shared__ float ssum[128], ssq[128];
  const int t = threadIdx.x;
  const int w = t >> 6, lane = t & 63;
  if (MODE != 2 && t < 128){ ssum[t] = 0.f; ssq[t] = 0.f; }
  const int part = (partArg >= 0) ? partArg : (int)blockIdx.y;
  const int eBase = blockIdx.x * 64;
  const int nBase = part * 128;
  const int lc = lane & 15, kg = lane >> 4;
  const int edge = eBase + w*16 + lc;
  const int nd0 = twi[edge], nd1 = twi[NE + edge], nd2 = twi[2*NE + edge];

  f32x4 acc[8];
  #pragma unroll
  for (int nf = 0; nf < 8; nf++){ acc[nf][0]=0.f; acc[nf][1]=0.f; acc[nf][2]=0.f; acc[nf][3]=0.f; }

  #pragma unroll
  for (int ks = 0; ks < 384; ks += 32){
    const int nd = (ks < 128) ? nd0 : ((ks < 256) ? nd1 : nd2);
    const int kin = (ks & 127) + kg*8;
    s16x8 a = *(const s16x8*)(xb + nd*DD + kin);
    #pragma unroll
    for (int nf = 0; nf < 8; nf++){
      const int col = nBase + nf*16 + lc;
      s16x8 b = *(const s16x8*)(Wcat + col*D3 + ks + kg*8);
      acc[nf] = __builtin_amdgcn_mfma_f32_16x16x32_bf16(a, b, acc[nf], 0, 0, 0);
    }
  }

  // wave-local repack (C frag: row=(lane>>4)*4+r, col=lane&15)
  #pragma unroll
  for (int nf = 0; nf < 8; nf++)
    #pragma unroll
    for (int r = 0; r < 4; r++)
      lt[w][kg*4 + r][nf*16 + lc] = acc[nf][r];

  const int rl = lane >> 5, cg = lane & 31;

  if (MODE == 2){
    const float mx = __uint_as_float(((const unsigned int*)stats)[ST_MAX]);
    const float invZ = 1.0f / stats[ST_SEXP];
    float sc[4], sh[4];
    #pragma unroll
    for (int j = 0; j < 4; j++){
      sc[j] = stats[ST_SCALE + nBase + cg*4 + j];
      sh[j] = stats[ST_SHIFT + nBase + cg*4 + j];
    }
    #pragma unroll
    for (int it = 0; it < 8; it++){
      const int row = it*2 + rl;
      const int e = eBase + w*16 + row;
      const int node = twi[part*NE + e];
      const int cv = cnt[part*NN + node];
      const float wgt = __expf(spost[e] - mx) * invZ / (float)cv;
      f32x4 v = *(const f32x4*)&lt[w][row][cg*4];
      #pragma unroll
      for (int j = 0; j < 4; j++){
        float val = wgt * fmaxf(v[j]*sc[j] + sh[j], 0.f);
        atomicAdd(&macc[(size_t)node*DD + cg*4 + j], val);
      }
    }
  } else {
    float ps0=0,ps1=0,ps2=0,ps3=0, pq0=0,pq1=0,pq2=0,pq3=0;
    #pragma unroll
    for (int it = 0; it < 8; it++){
      const int row = it*2 + rl;
      f32x4 v = *(const f32x4*)&lt[w][row][cg*4];
      if (MODE == 0){
        u16x4 o;
        o[0]=f2bf(v[0]); o[1]=f2bf(v[1]); o[2]=f2bf(v[2]); o[3]=f2bf(v[3]);
        *(u16x4*)(h + (size_t)(eBase + w*16 + row)*DD + cg*4) = o;
      }
      ps0 += v[0]; ps1 += v[1]; ps2 += v[2]; ps3 += v[3];
      pq0 += v[0]*v[0]; pq1 += v[1]*v[1]; pq2 += v[2]*v[2]; pq3 += v[3]*v[3];
    }
    ps0 += __shfl_xor(ps0, 32); ps1 += __shfl_xor(ps1, 32);
    ps2 += __shfl_xor(ps2, 32); ps3 += __shfl_xor(ps3, 32);
    pq0 += __shfl_xor(pq0, 32); pq1 += __shfl_xor(pq1, 32);
    pq2 += __shfl_xor(pq2, 32); pq3 += __shfl_xor(pq3, 32);
    __syncthreads();
    if (lane < 32){
      atomicAdd(&ssum[cg*4+0], ps0); atomicAdd(&ssum[cg*4+1], ps1);
      atomicAdd(&ssum[cg*4+2], ps2); atomicAdd(&ssum[cg*4+3], ps3);
      atomicAdd(&ssq [cg*4+0], pq0); atomicAdd(&ssq [cg*4+1], pq1);
      atomicAdd(&ssq [cg*4+2], pq2); atomicAdd(&ssq [cg*4+3], pq3);
    }
    __syncthreads();
    if (t < 128){
      atomicAdd(&stats[ST_SUM + nBase + t], ssum[t]);
      atomicAdd(&stats[ST_SQ  + nBase + t], ssq[t]);
    }
  }
}

// ---------------- score: sp[e] = feat . w1 ----------------
__global__ void g1_score(const unsigned short* __restrict__ xb,
                         const float* __restrict__ W1,
                         const int* __restrict__ twi,
                         float* __restrict__ sp, float* __restrict__ stats){
  const int lane = threadIdx.x & 63;
  const int wglob = (blockIdx.x*blockDim.x + threadIdx.x) >> 6;
  const int nw = (gridDim.x*blockDim.x) >> 6;
  float w1r[6];
  #pragma unroll
  for (int j = 0; j < 6; j++) w1r[j] = W1[j*64 + lane];
  float lsum = 0.f, lsq = 0.f;
  for (int e = wglob; e < NE; e += nw){
    const int n0 = twi[e], n1 = twi[NE+e], n2 = twi[2*NE+e];
    float s = 0.f;
    #pragma unroll
    for (int j = 0; j < 6; j++){
      int k = j*64 + lane;
      int nd = (k < 128) ? n0 : ((k < 256) ? n1 : n2);
      s += bf2f(xb[nd*DD + (k & 127)]) * w1r[j];
    }
    #pragma unroll
    for (int o = 32; o; o >>= 1) s += __shfl_xor(s, o);
    if (lane == 0){ sp[e] = s; lsum += s; lsq += s*s; }
  }
  if (lane == 0){
    atomicAdd(&stats[ST_SUM1], lsum);
    atomicAdd(&stats[ST_SQ1],  lsq);
  }
}

__global__ void sfin_score(const float* g1, const float* be1, float* __restrict__ stats){
  if (threadIdx.x == 0){
    float mu = stats[ST_SUM1] / (float)NE;
    float var = stats[ST_SQ1] / (float)NE - mu*mu;
    float sc = g1[0] * rsqrtf(var + EPSBN);
    stats[ST_SCALE1] = sc;
    stats[ST_SHIFT1] = be1[0] - mu*sc;
  }
}

__global__ void sfin_cols(const float* g, const float* be, float* __restrict__ stats, int part){
  int t = threadIdx.x;
  if (t < 128){
    int idx = part*128 + t;
    float mu = stats[ST_SUM + idx] / (float)NE;
    float var = stats[ST_SQ + idx] / (float)NE - mu*mu;
    float sc = g[t] * rsqrtf(var + EPSBN);
    stats[ST_SCALE + idx] = sc;
    stats[ST_SHIFT + idx] = be[t] - mu*sc;
  }
}

// ---------------- softmax pass 1: sp <- relu(BN(sp)), global max ----------------
__global__ void sm_max(float* __restrict__ sp, float* __restrict__ stats){
  const float sc = stats[ST_SCALE1], sh = stats[ST_SHIFT1];
  float lmax = 0.f;
  int stride = gridDim.x*blockDim.x;
  for (int i = blockIdx.x*blockDim.x + threadIdx.x; i < NE; i += stride){
    float s = fmaxf(sp[i]*sc + sh, 0.f);
    sp[i] = s;
    lmax = fmaxf(lmax, s);
  }
  #pragma unroll
  for (int o = 32; o; o >>= 1) lmax = fmaxf(lmax, __shfl_xor(lmax, o));
  __shared__ float red[4];
  if ((threadIdx.x & 63) == 0) red[threadIdx.x >> 6] = lmax;
  __syncthreads();
  if (threadIdx.x == 0){
    float m = fmaxf(fmaxf(red[0], red[1]), fmaxf(red[2], red[3]));
    atomicMax((unsigned int*)&stats[ST_MAX], __float_as_uint(m));
  }
}

__global__ void sm_sum(const float* __restrict__ sp, float* __restrict__ stats){
  const float mx = __uint_as_float(((const unsigned int*)stats)[ST_MAX]);
  float ls = 0.f;
  int stride = gridDim.x*blockDim.x;
  for (int i = blockIdx.x*blockDim.x + threadIdx.x; i < NE; i += stride)
    ls += __expf(sp[i] - mx);
  #pragma unroll
  for (int o = 32; o; o >>= 1) ls += __shfl_xor(ls, o);
  __shared__ float red[4];
  if ((threadIdx.x & 63) == 0) red[threadIdx.x >> 6] = ls;
  __syncthreads();
  if (threadIdx.x == 0)
    atomicAdd(&stats[ST_SEXP], red[0] + red[1] + red[2] + red[3]);
}

// -------- node-centric scatter-mean for one part (Plan A), macc += --------
__launch_bounds__(256)
__global__ void scatter_nc(const unsigned short* __restrict__ h,
                           const float* __restrict__ sp,
                           const int* __restrict__ cnt, const int* __restrict__ start,
                           const int* __restrict__ lists,
                           const float* __restrict__ stats,
                           float* __restrict__ macc, int part){
  const int w = threadIdx.x >> 6, lane = threadIdx.x & 63;
  const int n = blockIdx.x*4 + w;
  if (n >= NN) return;
  const float mx = __uint_as_float(((const unsigned int*)stats)[ST_MAX]);
  const float invZ = 1.0f / stats[ST_SEXP];
  const float sc0 = stats[ST_SCALE + part*128 + lane];
  const float sh0 = stats[ST_SHIFT + part*128 + lane];
  const float sc1 = stats[ST_SCALE + part*128 + 64 + lane];
  const float sh1 = stats[ST_SHIFT + part*128 + 64 + lane];
  const int cs = start[part*NN + n];
  const int c  = cnt[part*NN + n];
  float p0 = 0.f, p1 = 0.f;
  for (int j = 0; j < c; j++){
    const int e = lists[part*NE + cs + j];
    const float att = __expf(sp[e] - mx) * invZ;
    const float v0 = bf2f(h[(size_t)e*DD + lane]);
    const float v1 = bf2f(h[(size_t)e*DD + 64 + lane]);
    p0 += att * fmaxf(v0*sc0 + sh0, 0.f);
    p1 += att * fmaxf(v1*sc1 + sh1, 0.f);
  }
  if (c > 0){
    float ic = 1.f / (float)c;
    macc[(size_t)n*DD + lane]      += p0*ic;
    macc[(size_t)n*DD + 64 + lane] += p1*ic;
  }
}

// ---------------- zb = bf16(macc @ Wtw^T), fused col stats ----------------
__launch_bounds__(256)
__global__ void g2_gemm(const float* __restrict__ A,
                        const unsigned short* __restrict__ Wtwb,
                        unsigned short* __restrict__ zb,
                        float* __restrict__ stats){
  __shared__ float ssum[128], ssq[128];
  const int t = threadIdx.x;
  const int w = t >> 6, lane = t & 63;
  const int lc = lane & 15, kg = lane >> 4;
  if (t < 128){ ssum[t] = 0.f; ssq[t] = 0.f; }
  const int m0 = blockIdx.x*64 + w*16;
  const int arow = m0 + lc;
  f32x4 acc[8];
  #pragma unroll
  for (int nf = 0; nf < 8; nf++){ acc[nf][0]=0.f; acc[nf][1]=0.f; acc[nf][2]=0.f; acc[nf][3]=0.f; }
  #pragma unroll
  for (int ks = 0; ks < 128; ks += 32){
    s16x8 a;
    if (arow < NN){
      f32x4 a0 = *(const f32x4*)(A + (size_t)arow*DD + ks + kg*8);
      f32x4 a1 = *(const f32x4*)(A + (size_t)arow*DD + ks + kg*8 + 4);
      a[0]=(short)f2bf(a0[0]); a[1]=(short)f2bf(a0[1]); a[2]=(short)f2bf(a0[2]); a[3]=(short)f2bf(a0[3]);
      a[4]=(short)f2bf(a1[0]); a[5]=(short)f2bf(a1[1]); a[6]=(short)f2bf(a1[2]); a[7]=(short)f2bf(a1[3]);
    } else {
      a[0]=0;a[1]=0;a[2]=0;a[3]=0;a[4]=0;a[5]=0;a[6]=0;a[7]=0;
    }
    #pragma unroll
    for (int nf = 0; nf < 8; nf++){
      s16x8 b = *(const s16x8*)(Wtwb + (nf*16 + lc)*DD + ks + kg*8);
      acc[nf] = __builtin_amdgcn_mfma_f32_16x16x32_bf16(a, b, acc[nf], 0, 0, 0);
    }
  }
  float ps[8], pq[8];
  #pragma unroll
  for (int nf = 0; nf < 8; nf++){
    ps[nf] = 0.f; pq[nf] = 0.f;
    const int col = nf*16 + lc;
    #pragma unroll
    for (int r = 0; r < 4; r++){
      int row = m0 + kg*4 + r;
      if (row < NN){
        float v = acc[nf][r];
        zb[(size_t)row*DD + col] = f2bf(v);
        ps[nf] += v; pq[nf] += v*v;
      }
    }
  }
  __syncthreads();
  #pragma unroll
  for (int nf = 0; nf < 8; nf++){
    atomicAdd(&ssum[nf*16 + lc], ps[nf]);
    atomicAdd(&ssq [nf*16 + lc], pq[nf]);
  }
  __syncthreads();
  if (t < 128){
    atomicAdd(&stats[ST_SUM2 + t], ssum[t]);
    atomicAdd(&stats[ST_SQ2  + t], ssq[t]);
  }
}

__global__ void sfin2(const float* gtw, const float* betw, float* __restrict__ stats){
  int c = threadIdx.x;
  if (c < 128){
    float mu = stats[ST_SUM2 + c] / (float)NN;
    float var = stats[ST_SQ2 + c] / (float)NN - mu*mu;
    float sc = gtw[c] * rsqrtf(var + EPSBN);
    stats[ST_SCALE2 + c] = sc;
    stats[ST_SHIFT2 + c] = betw[c] - mu*sc;
  }
}

// ---------------- x += relu(BN(zb)); refresh bf16 copy ----------------
__global__ void fuse_update(const unsigned short* __restrict__ zb,
                            const float* __restrict__ stats,
                            float* __restrict__ xcur, unsigned short* __restrict__ xb){
  int stride = gridDim.x*blockDim.x;
  for (int i = blockIdx.x*blockDim.x + threadIdx.x; i < NN*DD; i += stride){
    int c = i & 127;
    float h = fmaxf(bf2f(zb[i])*stats[ST_SCALE2 + c] + stats[ST_SHIFT2 + c], 0.f);
    float nx = xcur[i] + h;
    xcur[i] = nx;
    xb[i] = f2bf(nx);
  }
}

extern "C" void kernel_launch(void* const* d_in, const int* in_sizes, int n_in,
                              void* d_out, int out_size, void* d_ws, size_t ws_size,
                              hipStream_t stream){
  const float* x    = (const float*)d_in[0];
  const int*   twi  = (const int*)d_in[1];
  const float* W_T  = (const float*)d_in[2];
  const float* W_M  = (const float*)d_in[3];
  const float* W_B  = (const float*)d_in[4];
  const float* W_1  = (const float*)d_in[5];
  const float* W_tw = (const float*)d_in[6];
  const float* g_T  = (const float*)d_in[8];
  const float* be_T = (const float*)d_in[9];
  const float* g_M  = (const float*)d_in[11];
  const float* be_M = (const float*)d_in[12];
  const float* g_B  = (const float*)d_in[14];
  const float* be_B = (const float*)d_in[15];
  const float* g_1  = (const float*)d_in[17];
  const float* be_1 = (const float*)d_in[18];
  const float* g_tw = (const float*)d_in[20];
  const float* be_tw= (const float*)d_in[21];
  float* xcur = (float*)d_out;

  char* ws = (char*)d_ws;
  size_t off = 0;
  auto take = [&](size_t b){ size_t o = off; off += (b + 255) & ~(size_t)255; return o; };
  float* stats = (float*)(ws + take(ST_TOTAL*4));
  unsigned short* Wcat = (unsigned short*)(ws + take(384*384*2));
  unsigned short* Wtwb = (unsigned short*)(ws + take(128*128*2));
  int* cnt    = (int*)(ws + take((size_t)3*NN*4));
  int* startA = (int*)(ws + take((size_t)3*NN*4));
  int* cursor = (int*)(ws + take((size_t)3*NN*4));
  int* lists  = (int*)(ws + take((size_t)3*NE*4));
  float* sp   = (float*)(ws + take((size_t)NE*4));
  unsigned short* xb = (unsigned short*)(ws + take((size_t)NN*DD*2));
  float* macc = (float*)(ws + take((size_t)NN*DD*4));
  unsigned short* zb = (unsigned short*)(ws + take((size_t)NN*DD*2));
  size_t needB = off;
  unsigned short* h = (unsigned short*)(ws + take((size_t)NE*DD*2));
  size_t needA = off;
  const bool planA = (ws_size >= needA);
  const bool okB   = (ws_size >= needB);
  if (!okB) return;  // cannot run at all; avoid faulting

  hipMemsetAsync(cnt, 0, (size_t)3*NN*4, stream);
  if (planA) hipMemsetAsync(cursor, 0, (size_t)3*NN*4, stream);
  init_x<<<2048, 256, 0, stream>>>(x, xcur, xb);
  csr_cnt<<<(NE+255)/256, 256, 0, stream>>>(twi, cnt);
  if (planA){
    csr_scan<<<1, 1024, 0, stream>>>(cnt, startA);
    csr_fill<<<(NE+255)/256, 256, 0, stream>>>(twi, startA, cursor, lists);
  }

  for (int l = 0; l < KL; l++){
    hipMemsetAsync(stats, 0, ST_TOTAL*4, stream);
    hipMemsetAsync(macc, 0, (size_t)NN*DD*4, stream);
    wprep<<<640, 256, 0, stream>>>(W_T + (size_t)l*DD*D3, W_M + (size_t)l*DD*D3,
                                   W_B + (size_t)l*DD*D3, W_tw + (size_t)l*DD*DD,
                                   Wcat, Wtwb);
    g1_score<<<512, 256, 0, stream>>>(xb, W_1 + (size_t)l*D3, twi, sp, stats);
    sfin_score<<<1, 64, 0, stream>>>(g_1 + l, be_1 + l, stats);
    sm_max<<<1024, 256, 0, stream>>>(sp, stats);
    sm_sum<<<1024, 256, 0, stream>>>(sp, stats);

    const float* gs[3]  = {g_T  + (size_t)l*DD, g_M  + (size_t)l*DD, g_B  + (size_t)l*DD};
    const float* bes[3] = {be_T + (size_t)l*DD, be_M + (size_t)l*DD, be_B + (size_t)l*DD};

    if (planA){
      for (int p = 0; p < 3; p++){
        g1_gemm<0><<<dim3(EB, 1), 256, 0, stream>>>(xb, Wcat, twi, cnt, sp, h, macc, stats, p);
        sfin_cols<<<1, 128, 0, stream>>>(gs[p], bes[p], stats, p);
        scatter_nc<<<(NN+3)/4, 256, 0, stream>>>(h, sp, cnt, startA, lists, stats, macc, p);
      }
    } else {
      g1_gemm<1><<<dim3(EB, 3), 256, 0, stream>>>(xb, Wcat, twi, cnt, sp, h, macc, stats, -1);
      for (int p = 0; p < 3; p++)
        sfin_cols<<<1, 128, 0, stream>>>(gs[p], bes[p], stats, p);
      g1_gemm<2><<<dim3(EB, 3), 256, 0, stream>>>(xb, Wcat, twi, cnt, sp, h, macc, stats, -1);
    }

    g2_gemm<<<(NN+63)/64, 256, 0, stream>>>(macc, Wtwb, zb, stats);
    sfin2<<<1, 128, 0, stream>>>(g_tw + (size_t)l*DD, be_tw + (size_t)l*DD, stats);
    fuse_update<<<2048, 256, 0, stream>>>(zb, stats, xcur, xb);
  }
}

// Round 3
// 3724.284 us; speedup vs baseline: 1.1280x; 1.1280x over previous
//
#include <hip/hip_runtime.h>

#define NN 100000
#define NE 400000
#define DD 128
#define D3 384
#define KL 2
#define EPSBN 1e-5f
#define EB (NE/64)
#define SCB ((NN + 1023) / 1024)   // 98 scan blocks per part

typedef __attribute__((ext_vector_type(8))) short s16x8;
typedef __attribute__((ext_vector_type(4))) float f32x4;
typedef __attribute__((ext_vector_type(4))) unsigned short u16x4;

// stats block float offsets
#define ST_SUM    0      // [384] col sums (T,M,B)
#define ST_SQ     384    // [384]
#define ST_SCALE  768    // [384]
#define ST_SHIFT  1152   // [384]
#define ST_SUM1   1536
#define ST_SQ1    1537
#define ST_MAX    1538
#define ST_SEXP   1539
#define ST_SCALE1 1540
#define ST_SHIFT1 1541
#define ST_SUM2   1542   // [128]
#define ST_SQ2    1670   // [128]
#define ST_SCALE2 1798   // [128]
#define ST_SHIFT2 1926   // [128]
#define ST_TOTAL  2054

__device__ __forceinline__ float bf2f(unsigned short u){
  return __uint_as_float(((unsigned int)u) << 16);
}
__device__ __forceinline__ unsigned short f2bf(float f){
  unsigned int x = __float_as_uint(f);
  x = x + 0x7FFFu + ((x >> 16) & 1u);
  return (unsigned short)(x >> 16);
}

// ---------------- init: x -> d_out (f32 working copy) + bf16 copy ----------------
__global__ void init_x(const float* __restrict__ x, float* __restrict__ xcur,
                       unsigned short* __restrict__ xb){
  int stride = gridDim.x * blockDim.x;
  for (int i = blockIdx.x*blockDim.x + threadIdx.x; i < NN*DD; i += stride){
    float v = x[i];
    xcur[i] = v;
    xb[i] = f2bf(v);
  }
}

// ---------------- weight prep (per layer) ----------------
__global__ void wprep(const float* __restrict__ WT, const float* __restrict__ WM,
                      const float* __restrict__ WB, const float* __restrict__ Wtw,
                      unsigned short* __restrict__ Wcat, unsigned short* __restrict__ Wtwb){
  int stride = gridDim.x * blockDim.x;
  int tid = blockIdx.x*blockDim.x + threadIdx.x;
  for (int i = tid; i < 384*384; i += stride){
    int n = i / 384, k = i - n*384;
    float v;
    if (n < 128)      v = WT[n*384 + k];
    else if (n < 256) v = WM[(n-128)*384 + k];
    else              v = WB[(n-256)*384 + k];
    Wcat[i] = f2bf(v);
  }
  for (int i = tid; i < 128*128; i += stride) Wtwb[i] = f2bf(Wtw[i]);
}

// ---------------- CSR build ----------------
__global__ void csr_cnt(const int* __restrict__ twi, int* __restrict__ cnt){
  int e = blockIdx.x*blockDim.x + threadIdx.x;
  if (e < NE){
    atomicAdd(&cnt[0*NN + twi[0*NE + e]], 1);
    atomicAdd(&cnt[1*NN + twi[1*NE + e]], 1);
    atomicAdd(&cnt[2*NN + twi[2*NE + e]], 1);
  }
}

// ---- hierarchical exclusive scan: (1) block sums, (2) scan sums, (3) fixup ----
__global__ void scan_bs(const int* __restrict__ cnt, int* __restrict__ bsums){
  const int p = blockIdx.y, b = blockIdx.x, t = threadIdx.x;
  const int base = b * 1024;
  int s = 0;
  #pragma unroll
  for (int j = 0; j < 4; j++){
    int i = base + t + j*256;
    if (i < NN) s += cnt[p*NN + i];
  }
  __shared__ int red[256];
  red[t] = s; __syncthreads();
  #pragma unroll
  for (int o = 128; o; o >>= 1){
    if (t < o) red[t] += red[t+o];
    __syncthreads();
  }
  if (t == 0) bsums[p*SCB + b] = red[0];
}

__global__ void scan_top(int* __restrict__ bsums){
  const int p = threadIdx.x;
  if (p < 3){
    int run = 0;
    for (int i = 0; i < SCB; i++){ int v = bsums[p*SCB + i]; bsums[p*SCB + i] = run; run += v; }
  }
}

__global__ void scan_fin(const int* __restrict__ cnt, const int* __restrict__ bsums,
                         int* __restrict__ start){
  const int p = blockIdx.y, b = blockIdx.x, t = threadIdx.x;
  const int base = b * 1024;
  int v[4]; int s = 0;
  #pragma unroll
  for (int j = 0; j < 4; j++){
    int i = base + t*4 + j;
    v[j] = (i < NN) ? cnt[p*NN + i] : 0;
    s += v[j];
  }
  __shared__ int red[256];
  red[t] = s; __syncthreads();
  // Hillis-Steele inclusive scan over thread sums
  #pragma unroll
  for (int o = 1; o < 256; o <<= 1){
    int other = (t >= o) ? red[t - o] : 0;
    __syncthreads();
    red[t] += other;
    __syncthreads();
  }
  int ex = red[t] - s + bsums[p*SCB + b];
  #pragma unroll
  for (int j = 0; j < 4; j++){
    int i = base + t*4 + j;
    if (i < NN) start[p*NN + i] = ex;
    ex += v[j];
  }
}

__global__ void csr_fill(const int* __restrict__ twi, const int* __restrict__ start,
                         int* __restrict__ cursor, int* __restrict__ lists){
  int e = blockIdx.x*blockDim.x + threadIdx.x;
  if (e < NE){
    #pragma unroll
    for (int p = 0; p < 3; p++){
      int n = twi[p*NE + e];
      int pos = atomicAdd(&cursor[p*NN + n], 1);
      lists[p*NE + start[p*NN + n] + pos] = e;
    }
  }
}

// ------------- gathered GEMM, one 128-col part per blockIdx.y / partArg -----------
// MODE 0: store bf16 h + BN col stats (Plan A)
// MODE 1: BN col stats only (Plan B pass 1)
// MODE 2: fused BN+ReLU+att/cnt epilogue, f32 atomic scatter into macc (Plan B p2)
template<int MODE>
__launch_bounds__(256)
__global__ void g1_gemm(const unsigned short* __restrict__ xb,
                        const unsigned short* __restrict__ Wcat,
                        const int* __restrict__ twi,
                        const int* __restrict__ cnt,
                        const float* __restrict__ spost,
                        unsigned short* __restrict__ h,
                        float* __restrict__ macc,
                        float* __restrict__ stats,
                        int partArg){
  __shared__ float lt[4][16][128];
  __shared__ float ssum[128], ssq[128];
  const int t = threadIdx.x;
  const int w = t >> 6, lane = t & 63;
  if (MODE != 2 && t < 128){ ssum[t] = 0.f; ssq[t] = 0.f; }
  const int part = (partArg >= 0) ? partArg : (int)blockIdx.y;
  const int eBase = blockIdx.x * 64;
  const int nBase = part * 128;
  const int lc = lane & 15, kg = lane >> 4;
  const int edge = eBase + w*16 + lc;
  const int nd0 = twi[edge], nd1 = twi[NE + edge], nd2 = twi[2*NE + edge];

  f32x4 acc[8];
  #pragma unroll
  for (int nf = 0; nf < 8; nf++){ acc[nf][0]=0.f; acc[nf][1]=0.f; acc[nf][2]=0.f; acc[nf][3]=0.f; }

  #pragma unroll
  for (int ks = 0; ks < 384; ks += 32){
    const int nd = (ks < 128) ? nd0 : ((ks < 256) ? nd1 : nd2);
    const int kin = (ks & 127) + kg*8;
    s16x8 a = *(const s16x8*)(xb + nd*DD + kin);
    #pragma unroll
    for (int nf = 0; nf < 8; nf++){
      const int col = nBase + nf*16 + lc;
      s16x8 b = *(const s16x8*)(Wcat + col*D3 + ks + kg*8);
      acc[nf] = __builtin_amdgcn_mfma_f32_16x16x32_bf16(a, b, acc[nf], 0, 0, 0);
    }
  }

  // wave-local repack (C frag: row=(lane>>4)*4+r, col=lane&15)
  #pragma unroll
  for (int nf = 0; nf < 8; nf++)
    #pragma unroll
    for (int r = 0; r < 4; r++)
      lt[w][kg*4 + r][nf*16 + lc] = acc[nf][r];

  const int rl = lane >> 5, cg = lane & 31;

  if (MODE == 2){
    const float mx = __uint_as_float(((const unsigned int*)stats)[ST_MAX]);
    const float invZ = 1.0f / stats[ST_SEXP];
    float sc[4], sh[4];
    #pragma unroll
    for (int j = 0; j < 4; j++){
      sc[j] = stats[ST_SCALE + nBase + cg*4 + j];
      sh[j] = stats[ST_SHIFT + nBase + cg*4 + j];
    }
    #pragma unroll
    for (int it = 0; it < 8; it++){
      const int row = it*2 + rl;
      const int e = eBase + w*16 + row;
      const int node = twi[part*NE + e];
      const int cv = cnt[part*NN + node];
      const float wgt = __expf(spost[e] - mx) * invZ / (float)cv;
      f32x4 v = *(const f32x4*)&lt[w][row][cg*4];
      #pragma unroll
      for (int j = 0; j < 4; j++){
        float val = wgt * fmaxf(v[j]*sc[j] + sh[j], 0.f);
        atomicAdd(&macc[(size_t)node*DD + cg*4 + j], val);
      }
    }
  } else {
    float ps0=0,ps1=0,ps2=0,ps3=0, pq0=0,pq1=0,pq2=0,pq3=0;
    #pragma unroll
    for (int it = 0; it < 8; it++){
      const int row = it*2 + rl;
      f32x4 v = *(const f32x4*)&lt[w][row][cg*4];
      if (MODE == 0){
        u16x4 o;
        o[0]=f2bf(v[0]); o[1]=f2bf(v[1]); o[2]=f2bf(v[2]); o[3]=f2bf(v[3]);
        *(u16x4*)(h + (size_t)(eBase + w*16 + row)*DD + cg*4) = o;
      }
      ps0 += v[0]; ps1 += v[1]; ps2 += v[2]; ps3 += v[3];
      pq0 += v[0]*v[0]; pq1 += v[1]*v[1]; pq2 += v[2]*v[2]; pq3 += v[3]*v[3];
    }
    ps0 += __shfl_xor(ps0, 32); ps1 += __shfl_xor(ps1, 32);
    ps2 += __shfl_xor(ps2, 32); ps3 += __shfl_xor(ps3, 32);
    pq0 += __shfl_xor(pq0, 32); pq1 += __shfl_xor(pq1, 32);
    pq2 += __shfl_xor(pq2, 32); pq3 += __shfl_xor(pq3, 32);
    __syncthreads();
    if (lane < 32){
      atomicAdd(&ssum[cg*4+0], ps0); atomicAdd(&ssum[cg*4+1], ps1);
      atomicAdd(&ssum[cg*4+2], ps2); atomicAdd(&ssum[cg*4+3], ps3);
      atomicAdd(&ssq [cg*4+0], pq0); atomicAdd(&ssq [cg*4+1], pq1);
      atomicAdd(&ssq [cg*4+2], pq2); atomicAdd(&ssq [cg*4+3], pq3);
    }
    __syncthreads();
    if (t < 128){
      atomicAdd(&stats[ST_SUM + nBase + t], ssum[t]);
      atomicAdd(&stats[ST_SQ  + nBase + t], ssq[t]);
    }
  }
}

// ---------------- score: sp[e] = feat . w1 ----------------
__global__ void g1_score(const unsigned short* __restrict__ xb,
                         const float* __restrict__ W1,
                         const int* __restrict__ twi,
                         float* __restrict__ sp, float* __restrict__ stats){
  const int lane = threadIdx.x & 63;
  const int wglob = (blockIdx.x*blockDim.x + threadIdx.x) >> 6;
  const int nw = (gridDim.x*blockDim.x) >> 6;
  float w1r[6];
  #pragma unroll
  for (int j = 0; j < 6; j++) w1r[j] = W1[j*64 + lane];
  float lsum = 0.f, lsq = 0.f;
  for (int e = wglob; e < NE; e += nw){
    const int n0 = twi[e], n1 = twi[NE+e], n2 = twi[2*NE+e];
    float s = 0.f;
    #pragma unroll
    for (int j = 0; j < 6; j++){
      int k = j*64 + lane;
      int nd = (k < 128) ? n0 : ((k < 256) ? n1 : n2);
      s += bf2f(xb[nd*DD + (k & 127)]) * w1r[j];
    }
    #pragma unroll
    for (int o = 32; o; o >>= 1) s += __shfl_xor(s, o);
    if (lane == 0){ sp[e] = s; lsum += s; lsq += s*s; }
  }
  if (lane == 0){
    atomicAdd(&stats[ST_SUM1], lsum);
    atomicAdd(&stats[ST_SQ1],  lsq);
  }
}

__global__ void sfin_score(const float* g1, const float* be1, float* __restrict__ stats){
  if (threadIdx.x == 0){
    float mu = stats[ST_SUM1] / (float)NE;
    float var = stats[ST_SQ1] / (float)NE - mu*mu;
    float sc = g1[0] * rsqrtf(var + EPSBN);
    stats[ST_SCALE1] = sc;
    stats[ST_SHIFT1] = be1[0] - mu*sc;
  }
}

__global__ void sfin_cols(const float* g, const float* be, float* __restrict__ stats, int part){
  int t = threadIdx.x;
  if (t < 128){
    int idx = part*128 + t;
    float mu = stats[ST_SUM + idx] / (float)NE;
    float var = stats[ST_SQ + idx] / (float)NE - mu*mu;
    float sc = g[t] * rsqrtf(var + EPSBN);
    stats[ST_SCALE + idx] = sc;
    stats[ST_SHIFT + idx] = be[t] - mu*sc;
  }
}

// ---------------- softmax pass 1: sp <- relu(BN(sp)), global max ----------------
__global__ void sm_max(float* __restrict__ sp, float* __restrict__ stats){
  const float sc = stats[ST_SCALE1], sh = stats[ST_SHIFT1];
  float lmax = 0.f;
  int stride = gridDim.x*blockDim.x;
  for (int i = blockIdx.x*blockDim.x + threadIdx.x; i < NE; i += stride){
    float s = fmaxf(sp[i]*sc + sh, 0.f);
    sp[i] = s;
    lmax = fmaxf(lmax, s);
  }
  #pragma unroll
  for (int o = 32; o; o >>= 1) lmax = fmaxf(lmax, __shfl_xor(lmax, o));
  __shared__ float red[4];
  if ((threadIdx.x & 63) == 0) red[threadIdx.x >> 6] = lmax;
  __syncthreads();
  if (threadIdx.x == 0){
    float m = fmaxf(fmaxf(red[0], red[1]), fmaxf(red[2], red[3]));
    atomicMax((unsigned int*)&stats[ST_MAX], __float_as_uint(m));
  }
}

__global__ void sm_sum(const float* __restrict__ sp, float* __restrict__ stats){
  const float mx = __uint_as_float(((const unsigned int*)stats)[ST_MAX]);
  float ls = 0.f;
  int stride = gridDim.x*blockDim.x;
  for (int i = blockIdx.x*blockDim.x + threadIdx.x; i < NE; i += stride)
    ls += __expf(sp[i] - mx);
  #pragma unroll
  for (int o = 32; o; o >>= 1) ls += __shfl_xor(ls, o);
  __shared__ float red[4];
  if ((threadIdx.x & 63) == 0) red[threadIdx.x >> 6] = ls;
  __syncthreads();
  if (threadIdx.x == 0)
    atomicAdd(&stats[ST_SEXP], red[0] + red[1] + red[2] + red[3]);
}

// -------- node-centric scatter-mean for one part (Plan A), macc += --------
__launch_bounds__(256)
__global__ void scatter_nc(const unsigned short* __restrict__ h,
                           const float* __restrict__ sp,
                           const int* __restrict__ cnt, const int* __restrict__ start,
                           const int* __restrict__ lists,
                           const float* __restrict__ stats,
                           float* __restrict__ macc, int part){
  const int w = threadIdx.x >> 6, lane = threadIdx.x & 63;
  const int n = blockIdx.x*4 + w;
  if (n >= NN) return;
  const float mx = __uint_as_float(((const unsigned int*)stats)[ST_MAX]);
  const float invZ = 1.0f / stats[ST_SEXP];
  const float sc0 = stats[ST_SCALE + part*128 + lane];
  const float sh0 = stats[ST_SHIFT + part*128 + lane];
  const float sc1 = stats[ST_SCALE + part*128 + 64 + lane];
  const float sh1 = stats[ST_SHIFT + part*128 + 64 + lane];
  const int cs = start[part*NN + n];
  const int c  = cnt[part*NN + n];
  float p0 = 0.f, p1 = 0.f;
  for (int j = 0; j < c; j++){
    const int e = lists[part*NE + cs + j];
    const float att = __expf(sp[e] - mx) * invZ;
    const float v0 = bf2f(h[(size_t)e*DD + lane]);
    const float v1 = bf2f(h[(size_t)e*DD + 64 + lane]);
    p0 += att * fmaxf(v0*sc0 + sh0, 0.f);
    p1 += att * fmaxf(v1*sc1 + sh1, 0.f);
  }
  if (c > 0){
    float ic = 1.f / (float)c;
    macc[(size_t)n*DD + lane]      += p0*ic;
    macc[(size_t)n*DD + 64 + lane] += p1*ic;
  }
}

// ---------------- zb = bf16(macc @ Wtw^T), fused col stats ----------------
__launch_bounds__(256)
__global__ void g2_gemm(const float* __restrict__ A,
                        const unsigned short* __restrict__ Wtwb,
                        unsigned short* __restrict__ zb,
                        float* __restrict__ stats){
  __shared__ float ssum[128], ssq[128];
  const int t = threadIdx.x;
  const int w = t >> 6, lane = t & 63;
  const int lc = lane & 15, kg = lane >> 4;
  if (t < 128){ ssum[t] = 0.f; ssq[t] = 0.f; }
  const int m0 = blockIdx.x*64 + w*16;
  const int arow = m0 + lc;
  f32x4 acc[8];
  #pragma unroll
  for (int nf = 0; nf < 8; nf++){ acc[nf][0]=0.f; acc[nf][1]=0.f; acc[nf][2]=0.f; acc[nf][3]=0.f; }
  #pragma unroll
  for (int ks = 0; ks < 128; ks += 32){
    s16x8 a;
    if (arow < NN){
      f32x4 a0 = *(const f32x4*)(A + (size_t)arow*DD + ks + kg*8);
      f32x4 a1 = *(const f32x4*)(A + (size_t)arow*DD + ks + kg*8 + 4);
      a[0]=(short)f2bf(a0[0]); a[1]=(short)f2bf(a0[1]); a[2]=(short)f2bf(a0[2]); a[3]=(short)f2bf(a0[3]);
      a[4]=(short)f2bf(a1[0]); a[5]=(short)f2bf(a1[1]); a[6]=(short)f2bf(a1[2]); a[7]=(short)f2bf(a1[3]);
    } else {
      a[0]=0;a[1]=0;a[2]=0;a[3]=0;a[4]=0;a[5]=0;a[6]=0;a[7]=0;
    }
    #pragma unroll
    for (int nf = 0; nf < 8; nf++){
      s16x8 b = *(const s16x8*)(Wtwb + (nf*16 + lc)*DD + ks + kg*8);
      acc[nf] = __builtin_amdgcn_mfma_f32_16x16x32_bf16(a, b, acc[nf], 0, 0, 0);
    }
  }
  float ps[8], pq[8];
  #pragma unroll
  for (int nf = 0; nf < 8; nf++){
    ps[nf] = 0.f; pq[nf] = 0.f;
    const int col = nf*16 + lc;
    #pragma unroll
    for (int r = 0; r < 4; r++){
      int row = m0 + kg*4 + r;
      if (row < NN){
        float v = acc[nf][r];
        zb[(size_t)row*DD + col] = f2bf(v);
        ps[nf] += v; pq[nf] += v*v;
      }
    }
  }
  __syncthreads();
  #pragma unroll
  for (int nf = 0; nf < 8; nf++){
    atomicAdd(&ssum[nf*16 + lc], ps[nf]);
    atomicAdd(&ssq [nf*16 + lc], pq[nf]);
  }
  __syncthreads();
  if (t < 128){
    atomicAdd(&stats[ST_SUM2 + t], ssum[t]);
    atomicAdd(&stats[ST_SQ2  + t], ssq[t]);
  }
}

__global__ void sfin2(const float* gtw, const float* betw, float* __restrict__ stats){
  int c = threadIdx.x;
  if (c < 128){
    float mu = stats[ST_SUM2 + c] / (float)NN;
    float var = stats[ST_SQ2 + c] / (float)NN - mu*mu;
    float sc = gtw[c] * rsqrtf(var + EPSBN);
    stats[ST_SCALE2 + c] = sc;
    stats[ST_SHIFT2 + c] = betw[c] - mu*sc;
  }
}

// ---------------- x += relu(BN(zb)); refresh bf16 copy ----------------
__global__ void fuse_update(const unsigned short* __restrict__ zb,
                            const float* __restrict__ stats,
                            float* __restrict__ xcur, unsigned short* __restrict__ xb){
  int stride = gridDim.x*blockDim.x;
  for (int i = blockIdx.x*blockDim.x + threadIdx.x; i < NN*DD; i += stride){
    int c = i & 127;
    float h = fmaxf(bf2f(zb[i])*stats[ST_SCALE2 + c] + stats[ST_SHIFT2 + c], 0.f);
    float nx = xcur[i] + h;
    xcur[i] = nx;
    xb[i] = f2bf(nx);
  }
}

extern "C" void kernel_launch(void* const* d_in, const int* in_sizes, int n_in,
                              void* d_out, int out_size, void* d_ws, size_t ws_size,
                              hipStream_t stream){
  const float* x    = (const float*)d_in[0];
  const int*   twi  = (const int*)d_in[1];
  const float* W_T  = (const float*)d_in[2];
  const float* W_M  = (const float*)d_in[3];
  const float* W_B  = (const float*)d_in[4];
  const float* W_1  = (const float*)d_in[5];
  const float* W_tw = (const float*)d_in[6];
  const float* g_T  = (const float*)d_in[8];
  const float* be_T = (const float*)d_in[9];
  const float* g_M  = (const float*)d_in[11];
  const float* be_M = (const float*)d_in[12];
  const float* g_B  = (const float*)d_in[14];
  const float* be_B = (const float*)d_in[15];
  const float* g_1  = (const float*)d_in[17];
  const float* be_1 = (const float*)d_in[18];
  const float* g_tw = (const float*)d_in[20];
  const float* be_tw= (const float*)d_in[21];
  float* xcur = (float*)d_out;

  char* ws = (char*)d_ws;
  size_t off = 0;
  auto take = [&](size_t b){ size_t o = off; off += (b + 255) & ~(size_t)255; return o; };
  float* stats = (float*)(ws + take(ST_TOTAL*4));
  unsigned short* Wcat = (unsigned short*)(ws + take(384*384*2));
  unsigned short* Wtwb = (unsigned short*)(ws + take(128*128*2));
  int* bsums  = (int*)(ws + take((size_t)3*SCB*4));
  int* cnt    = (int*)(ws + take((size_t)3*NN*4));
  int* startA = (int*)(ws + take((size_t)3*NN*4));
  int* cursor = (int*)(ws + take((size_t)3*NN*4));
  int* lists  = (int*)(ws + take((size_t)3*NE*4));
  float* sp   = (float*)(ws + take((size_t)NE*4));
  unsigned short* xb = (unsigned short*)(ws + take((size_t)NN*DD*2));
  float* macc = (float*)(ws + take((size_t)NN*DD*4));
  unsigned short* zb = (unsigned short*)(ws + take((size_t)NN*DD*2));
  size_t needB = off;
  unsigned short* h = (unsigned short*)(ws + take((size_t)NE*DD*2));
  size_t needA = off;
  const bool planA = (ws_size >= needA);
  const bool okB   = (ws_size >= needB);
  if (!okB) return;  // cannot run at all; avoid faulting

  hipMemsetAsync(cnt, 0, (size_t)3*NN*4, stream);
  if (planA) hipMemsetAsync(cursor, 0, (size_t)3*NN*4, stream);
  init_x<<<2048, 256, 0, stream>>>(x, xcur, xb);
  csr_cnt<<<(NE+255)/256, 256, 0, stream>>>(twi, cnt);
  if (planA){
    scan_bs<<<dim3(SCB, 3), 256, 0, stream>>>(cnt, bsums);
    scan_top<<<1, 64, 0, stream>>>(bsums);
    scan_fin<<<dim3(SCB, 3), 256, 0, stream>>>(cnt, bsums, startA);
    csr_fill<<<(NE+255)/256, 256, 0, stream>>>(twi, startA, cursor, lists);
  }

  for (int l = 0; l < KL; l++){
    hipMemsetAsync(stats, 0, ST_TOTAL*4, stream);
    hipMemsetAsync(macc, 0, (size_t)NN*DD*4, stream);
    wprep<<<640, 256, 0, stream>>>(W_T + (size_t)l*DD*D3, W_M + (size_t)l*DD*D3,
                                   W_B + (size_t)l*DD*D3, W_tw + (size_t)l*DD*DD,
                                   Wcat, Wtwb);
    g1_score<<<512, 256, 0, stream>>>(xb, W_1 + (size_t)l*D3, twi, sp, stats);
    sfin_score<<<1, 64, 0, stream>>>(g_1 + l, be_1 + l, stats);
    sm_max<<<1024, 256, 0, stream>>>(sp, stats);
    sm_sum<<<1024, 256, 0, stream>>>(sp, stats);

    const float* gs[3]  = {g_T  + (size_t)l*DD, g_M  + (size_t)l*DD, g_B  + (size_t)l*DD};
    const float* bes[3] = {be_T + (size_t)l*DD, be_M + (size_t)l*DD, be_B + (size_t)l*DD};

    if (planA){
      for (int p = 0; p < 3; p++){
        g1_gemm<0><<<dim3(EB, 1), 256, 0, stream>>>(xb, Wcat, twi, cnt, sp, h, macc, stats, p);
        sfin_cols<<<1, 128, 0, stream>>>(gs[p], bes[p], stats, p);
        scatter_nc<<<(NN+3)/4, 256, 0, stream>>>(h, sp, cnt, startA, lists, stats, macc, p);
      }
    } else {
      g1_gemm<1><<<dim3(EB, 3), 256, 0, stream>>>(xb, Wcat, twi, cnt, sp, h, macc, stats, -1);
      for (int p = 0; p < 3; p++)
        sfin_cols<<<1, 128, 0, stream>>>(gs[p], bes[p], stats, p);
      g1_gemm<2><<<dim3(EB, 3), 256, 0, stream>>>(xb, Wcat, twi, cnt, sp, h, macc, stats, -1);
    }

    g2_gemm<<<(NN+63)/64, 256, 0, stream>>>(macc, Wtwb, zb, stats);
    sfin2<<<1, 128, 0, stream>>>(g_tw + (size_t)l*DD, be_tw + (size_t)l*DD, stats);
    fuse_update<<<2048, 256, 0, stream>>>(zb, stats, xcur, xb);
  }
}

// Round 4
// 3274.868 us; speedup vs baseline: 1.2828x; 1.1372x over previous
//
#include <hip/hip_runtime.h>

#define NN 100000
#define NE 400000
#define DD 128
#define D3 384
#define KL 2
#define EPSBN 1e-5f
#define EB (NE/64)
#define SCB ((NN + 1023) / 1024)

typedef __attribute__((ext_vector_type(8))) short s16x8;
typedef __attribute__((ext_vector_type(4))) float f32x4;
typedef __attribute__((ext_vector_type(4))) unsigned short u16x4;

#define ST_SUM    0      // [384]
#define ST_SQ     384    // [384]
#define ST_SCALE  768    // [384]
#define ST_SHIFT  1152   // [384]
#define ST_SUM1   1536
#define ST_SQ1    1537
#define ST_MAX    1538
#define ST_SEXP   1539
#define ST_SCALE1 1540
#define ST_SHIFT1 1541
#define ST_SUM2   1542   // [128]
#define ST_SQ2    1670   // [128]
#define ST_SCALE2 1798   // [128]
#define ST_SHIFT2 1926   // [128]
#define ST_TOTAL  2054

__device__ __forceinline__ float bf2f(unsigned short u){
  return __uint_as_float(((unsigned int)u) << 16);
}
__device__ __forceinline__ unsigned short f2bf(float f){
  unsigned int x = __float_as_uint(f);
  x = x + 0x7FFFu + ((x >> 16) & 1u);
  return (unsigned short)(x >> 16);
}

// ---------------- init: x -> xcur (f32) + xb (bf16), vectorized ----------------
__global__ void init_x(const float* __restrict__ x, float* __restrict__ xcur,
                       unsigned short* __restrict__ xb){
  const int tot = NN*DD/4;
  int stride = gridDim.x * blockDim.x;
  for (int i = blockIdx.x*blockDim.x + threadIdx.x; i < tot; i += stride){
    f32x4 v = ((const f32x4*)x)[i];
    ((f32x4*)xcur)[i] = v;
    u16x4 o; o[0]=f2bf(v[0]); o[1]=f2bf(v[1]); o[2]=f2bf(v[2]); o[3]=f2bf(v[3]);
    ((u16x4*)xb)[i] = o;
  }
}

// ---------------- weight prep (per layer) ----------------
__global__ void wprep(const float* __restrict__ WT, const float* __restrict__ WM,
                      const float* __restrict__ WB, const float* __restrict__ Wtw,
                      unsigned short* __restrict__ Wcat, unsigned short* __restrict__ Wtwb){
  int stride = gridDim.x * blockDim.x;
  int tid = blockIdx.x*blockDim.x + threadIdx.x;
  for (int i = tid; i < 384*384; i += stride){
    int n = i / 384, k = i - n*384;
    float v;
    if (n < 128)      v = WT[n*384 + k];
    else if (n < 256) v = WM[(n-128)*384 + k];
    else              v = WB[(n-256)*384 + k];
    Wcat[i] = f2bf(v);
  }
  for (int i = tid; i < 128*128; i += stride) Wtwb[i] = f2bf(Wtw[i]);
}

// ---------------- CSR build ----------------
__global__ void csr_cnt(const int* __restrict__ twi, int* __restrict__ cnt){
  int e = blockIdx.x*blockDim.x + threadIdx.x;
  if (e < NE){
    atomicAdd(&cnt[0*NN + twi[0*NE + e]], 1);
    atomicAdd(&cnt[1*NN + twi[1*NE + e]], 1);
    atomicAdd(&cnt[2*NN + twi[2*NE + e]], 1);
  }
}

__global__ void scan_bs(const int* __restrict__ cnt, int* __restrict__ bsums){
  const int p = blockIdx.y, b = blockIdx.x, t = threadIdx.x;
  const int base = b * 1024;
  int s = 0;
  #pragma unroll
  for (int j = 0; j < 4; j++){
    int i = base + t + j*256;
    if (i < NN) s += cnt[p*NN + i];
  }
  __shared__ int red[256];
  red[t] = s; __syncthreads();
  #pragma unroll
  for (int o = 128; o; o >>= 1){
    if (t < o) red[t] += red[t+o];
    __syncthreads();
  }
  if (t == 0) bsums[p*SCB + b] = red[0];
}

__global__ void scan_top(int* __restrict__ bsums){
  const int p = threadIdx.x;
  if (p < 3){
    int run = 0;
    for (int i = 0; i < SCB; i++){ int v = bsums[p*SCB + i]; bsums[p*SCB + i] = run; run += v; }
  }
}

__global__ void scan_fin(const int* __restrict__ cnt, const int* __restrict__ bsums,
                         int* __restrict__ start){
  const int p = blockIdx.y, b = blockIdx.x, t = threadIdx.x;
  const int base = b * 1024;
  int v[4]; int s = 0;
  #pragma unroll
  for (int j = 0; j < 4; j++){
    int i = base + t*4 + j;
    v[j] = (i < NN) ? cnt[p*NN + i] : 0;
    s += v[j];
  }
  __shared__ int red[256];
  red[t] = s; __syncthreads();
  #pragma unroll
  for (int o = 1; o < 256; o <<= 1){
    int other = (t >= o) ? red[t - o] : 0;
    __syncthreads();
    red[t] += other;
    __syncthreads();
  }
  int ex = red[t] - s + bsums[p*SCB + b];
  #pragma unroll
  for (int j = 0; j < 4; j++){
    int i = base + t*4 + j;
    if (i < NN) start[p*NN + i] = ex;
    ex += v[j];
  }
}

__global__ void csr_fill(const int* __restrict__ twi, const int* __restrict__ start,
                         int* __restrict__ cursor, int* __restrict__ lists){
  int e = blockIdx.x*blockDim.x + threadIdx.x;
  if (e < NE){
    #pragma unroll
    for (int p = 0; p < 3; p++){
      int n = twi[p*NE + e];
      int pos = atomicAdd(&cursor[p*NN + n], 1);
      lists[p*NE + start[p*NN + n] + pos] = e;
    }
  }
}

// ------------- gathered GEMM with register A-prefetch -----------
// FUSED=1: all 3 parts + score in one dispatch (h has 3 planes)
// FUSED=0: one part per dispatch (h single plane); score folded into part 0
template<int FUSED>
__launch_bounds__(256)
__global__ void g1k(const unsigned short* __restrict__ xb,
                    const unsigned short* __restrict__ Wcat,
                    const float* __restrict__ W1,
                    const int* __restrict__ twi,
                    unsigned short* __restrict__ h,
                    float* __restrict__ sp,
                    float* __restrict__ stats,
                    int part){
  __shared__ float lt[4][16][128];
  __shared__ float ssum[128], ssq[128];
  __shared__ float s1s[4], s1q[4];
  const int t = threadIdx.x;
  const int w = t >> 6, lane = t & 63;
  const int lc = lane & 15, kg = lane >> 4;
  const int eBase = blockIdx.x * 64;
  const int edge = eBase + w*16 + lc;
  const int nd0 = twi[edge], nd1 = twi[NE + edge], nd2 = twi[2*NE + edge];

  // ---- prefetch ALL 12 A-gather fragments into registers (latency overlap) ----
  s16x8 areg[12];
  #pragma unroll
  for (int ks = 0; ks < 12; ks++){
    const int nd = (ks < 4) ? nd0 : ((ks < 8) ? nd1 : nd2);
    areg[ks] = *(const s16x8*)(xb + (size_t)nd*DD + (ks & 3)*32 + kg*8);
  }

  // ---- score (fused): s[e] = feat . w1 from A-regs ----
  if (FUSED || part == 0){
    float sa = 0.f;
    #pragma unroll
    for (int ks = 0; ks < 12; ks++){
      const float* wp = W1 + ks*32 + kg*8;
      f32x4 w0 = *(const f32x4*)wp;
      f32x4 w1v = *(const f32x4*)(wp + 4);
      #pragma unroll
      for (int j = 0; j < 4; j++) sa += bf2f((unsigned short)areg[ks][j])   * w0[j];
      #pragma unroll
      for (int j = 0; j < 4; j++) sa += bf2f((unsigned short)areg[ks][4+j]) * w1v[j];
    }
    sa += __shfl_xor(sa, 16);
    sa += __shfl_xor(sa, 32);
    if (lane < 16) sp[edge] = sa;
    float sv = (lane < 16) ? sa : 0.f;
    float qv = sv*sv;
    #pragma unroll
    for (int o = 8; o; o >>= 1){ sv += __shfl_xor(sv, o); qv += __shfl_xor(qv, o); }
    if (lane == 0){ s1s[w] = sv; s1q[w] = qv; }
    __syncthreads();
    if (t == 0){
      atomicAdd(&stats[ST_SUM1], s1s[0]+s1s[1]+s1s[2]+s1s[3]);
      atomicAdd(&stats[ST_SQ1],  s1q[0]+s1q[1]+s1q[2]+s1q[3]);
    }
  }

  const int nparts = FUSED ? 3 : 1;
  for (int pp = 0; pp < nparts; pp++){
    const int p = FUSED ? pp : part;
    if (t < 128){ ssum[t] = 0.f; ssq[t] = 0.f; }
    __syncthreads();

    f32x4 acc[8];
    #pragma unroll
    for (int nf = 0; nf < 8; nf++){ acc[nf][0]=0.f; acc[nf][1]=0.f; acc[nf][2]=0.f; acc[nf][3]=0.f; }

    const unsigned short* wb = Wcat + (size_t)(p*128 + lc)*D3 + kg*8;
    #pragma unroll
    for (int ks = 0; ks < 12; ks++){
      #pragma unroll
      for (int nf = 0; nf < 8; nf++){
        s16x8 b = *(const s16x8*)(wb + nf*16*D3 + ks*32);
        acc[nf] = __builtin_amdgcn_mfma_f32_16x16x32_bf16(areg[ks], b, acc[nf], 0, 0, 0);
      }
    }

    // wave-local repack (C frag: row=(lane>>4)*4+r, col=lane&15)
    #pragma unroll
    for (int nf = 0; nf < 8; nf++)
      #pragma unroll
      for (int r = 0; r < 4; r++)
        lt[w][kg*4 + r][nf*16 + lc] = acc[nf][r];

    unsigned short* hp = h + (FUSED ? (size_t)pp*NE*DD : 0);
    const int rl = lane >> 5, cg = lane & 31;
    float ps0=0,ps1=0,ps2=0,ps3=0, pq0=0,pq1=0,pq2=0,pq3=0;
    #pragma unroll
    for (int it = 0; it < 8; it++){
      const int row = it*2 + rl;
      f32x4 v = *(const f32x4*)&lt[w][row][cg*4];
      u16x4 o;
      o[0]=f2bf(v[0]); o[1]=f2bf(v[1]); o[2]=f2bf(v[2]); o[3]=f2bf(v[3]);
      *(u16x4*)(hp + (size_t)(eBase + w*16 + row)*DD + cg*4) = o;
      ps0 += v[0]; ps1 += v[1]; ps2 += v[2]; ps3 += v[3];
      pq0 += v[0]*v[0]; pq1 += v[1]*v[1]; pq2 += v[2]*v[2]; pq3 += v[3]*v[3];
    }
    ps0 += __shfl_xor(ps0, 32); ps1 += __shfl_xor(ps1, 32);
    ps2 += __shfl_xor(ps2, 32); ps3 += __shfl_xor(ps3, 32);
    pq0 += __shfl_xor(pq0, 32); pq1 += __shfl_xor(pq1, 32);
    pq2 += __shfl_xor(pq2, 32); pq3 += __shfl_xor(pq3, 32);
    if (lane < 32){
      atomicAdd(&ssum[cg*4+0], ps0); atomicAdd(&ssum[cg*4+1], ps1);
      atomicAdd(&ssum[cg*4+2], ps2); atomicAdd(&ssum[cg*4+3], ps3);
      atomicAdd(&ssq [cg*4+0], pq0); atomicAdd(&ssq [cg*4+1], pq1);
      atomicAdd(&ssq [cg*4+2], pq2); atomicAdd(&ssq [cg*4+3], pq3);
    }
    __syncthreads();
    if (t < 128){
      atomicAdd(&stats[ST_SUM + p*128 + t], ssum[t]);
      atomicAdd(&stats[ST_SQ  + p*128 + t], ssq[t]);
    }
    if (pp + 1 < nparts) __syncthreads();
  }
}

// ---------------- BN finalize ----------------
__global__ void sfin_score(const float* g1, const float* be1, float* __restrict__ stats){
  if (threadIdx.x == 0){
    float mu = stats[ST_SUM1] / (float)NE;
    float var = stats[ST_SQ1] / (float)NE - mu*mu;
    float sc = g1[0] * rsqrtf(var + EPSBN);
    stats[ST_SCALE1] = sc;
    stats[ST_SHIFT1] = be1[0] - mu*sc;
  }
}

__global__ void sfin_cols(const float* g, const float* be, float* __restrict__ stats, int part){
  int t = threadIdx.x;
  if (t < 128){
    int idx = part*128 + t;
    float mu = stats[ST_SUM + idx] / (float)NE;
    float var = stats[ST_SQ + idx] / (float)NE - mu*mu;
    float sc = g[t] * rsqrtf(var + EPSBN);
    stats[ST_SCALE + idx] = sc;
    stats[ST_SHIFT + idx] = be[t] - mu*sc;
  }
}

__global__ void sfin_all(const float* gT, const float* beT, const float* gM, const float* beM,
                         const float* gB, const float* beB, const float* g1, const float* be1,
                         float* __restrict__ stats){
  int t = threadIdx.x;
  if (t < 384){
    float mu = stats[ST_SUM + t] / (float)NE;
    float var = stats[ST_SQ + t] / (float)NE - mu*mu;
    float g, be;
    if (t < 128)      { g = gT[t];     be = beT[t]; }
    else if (t < 256) { g = gM[t-128]; be = beM[t-128]; }
    else              { g = gB[t-256]; be = beB[t-256]; }
    float sc = g * rsqrtf(var + EPSBN);
    stats[ST_SCALE + t] = sc;
    stats[ST_SHIFT + t] = be - mu*sc;
  } else if (t == 384){
    float mu = stats[ST_SUM1] / (float)NE;
    float var = stats[ST_SQ1] / (float)NE - mu*mu;
    float sc = g1[0] * rsqrtf(var + EPSBN);
    stats[ST_SCALE1] = sc;
    stats[ST_SHIFT1] = be1[0] - mu*sc;
  }
}

// ---------------- softmax: max, sum, att-in-place ----------------
__global__ void sm_max(float* __restrict__ sp, float* __restrict__ stats){
  const float sc = stats[ST_SCALE1], sh = stats[ST_SHIFT1];
  float lmax = 0.f;
  int stride = gridDim.x*blockDim.x;
  for (int i = blockIdx.x*blockDim.x + threadIdx.x; i < NE; i += stride){
    float s = fmaxf(sp[i]*sc + sh, 0.f);
    sp[i] = s;
    lmax = fmaxf(lmax, s);
  }
  #pragma unroll
  for (int o = 32; o; o >>= 1) lmax = fmaxf(lmax, __shfl_xor(lmax, o));
  __shared__ float red[4];
  if ((threadIdx.x & 63) == 0) red[threadIdx.x >> 6] = lmax;
  __syncthreads();
  if (threadIdx.x == 0){
    float m = fmaxf(fmaxf(red[0], red[1]), fmaxf(red[2], red[3]));
    atomicMax((unsigned int*)&stats[ST_MAX], __float_as_uint(m));
  }
}

__global__ void sm_sum(const float* __restrict__ sp, float* __restrict__ stats){
  const float mx = __uint_as_float(((const unsigned int*)stats)[ST_MAX]);
  float ls = 0.f;
  int stride = gridDim.x*blockDim.x;
  for (int i = blockIdx.x*blockDim.x + threadIdx.x; i < NE; i += stride)
    ls += __expf(sp[i] - mx);
  #pragma unroll
  for (int o = 32; o; o >>= 1) ls += __shfl_xor(ls, o);
  __shared__ float red[4];
  if ((threadIdx.x & 63) == 0) red[threadIdx.x >> 6] = ls;
  __syncthreads();
  if (threadIdx.x == 0)
    atomicAdd(&stats[ST_SEXP], red[0] + red[1] + red[2] + red[3]);
}

__global__ void sm_att(float* __restrict__ sp, const float* __restrict__ stats){
  const float mx = __uint_as_float(((const unsigned int*)stats)[ST_MAX]);
  const float invZ = 1.0f / stats[ST_SEXP];
  int stride = gridDim.x*blockDim.x;
  for (int i = blockIdx.x*blockDim.x + threadIdx.x; i < NE; i += stride)
    sp[i] = __expf(sp[i] - mx) * invZ;
}

// -------- node-centric scatter-mean; FUSED=1 covers all parts, writes macc --------
template<int FUSED>
__launch_bounds__(256)
__global__ void scat(const unsigned short* __restrict__ h,
                     const float* __restrict__ att,
                     const int* __restrict__ cnt, const int* __restrict__ start,
                     const int* __restrict__ lists,
                     const float* __restrict__ stats,
                     float* __restrict__ macc, int part){
  const int w = threadIdx.x >> 6, lane = threadIdx.x & 63;
  const int n = blockIdx.x*4 + w;
  if (n >= NN) return;
  float a0 = 0.f, a1 = 0.f;
  const int nparts = FUSED ? 3 : 1;
  for (int pp = 0; pp < nparts; pp++){
    const int p = FUSED ? pp : part;
    const unsigned short* hp = h + (FUSED ? (size_t)pp*NE*DD : 0);
    const float sc0 = stats[ST_SCALE + p*128 + lane];
    const float sh0 = stats[ST_SHIFT + p*128 + lane];
    const float sc1 = stats[ST_SCALE + p*128 + 64 + lane];
    const float sh1 = stats[ST_SHIFT + p*128 + 64 + lane];
    const int cs = start[p*NN + n];
    const int c  = cnt[p*NN + n];
    float p0 = 0.f, p1 = 0.f;
    for (int j = 0; j < c; j++){
      const int e = lists[p*NE + cs + j];
      const float av = att[e];
      const float v0 = bf2f(hp[(size_t)e*DD + lane]);
      const float v1 = bf2f(hp[(size_t)e*DD + 64 + lane]);
      p0 += av * fmaxf(v0*sc0 + sh0, 0.f);
      p1 += av * fmaxf(v1*sc1 + sh1, 0.f);
    }
    if (c > 0){ float ic = 1.f / (float)c; a0 += p0*ic; a1 += p1*ic; }
  }
  if (FUSED){
    macc[(size_t)n*DD + lane]      = a0;
    macc[(size_t)n*DD + 64 + lane] = a1;
  } else {
    macc[(size_t)n*DD + lane]      += a0;
    macc[(size_t)n*DD + 64 + lane] += a1;
  }
}

// ---------------- zb = bf16(macc @ Wtw^T), fused col stats ----------------
__launch_bounds__(256)
__global__ void g2_gemm(const float* __restrict__ A,
                        const unsigned short* __restrict__ Wtwb,
                        unsigned short* __restrict__ zb,
                        float* __restrict__ stats){
  __shared__ float ssum[128], ssq[128];
  const int t = threadIdx.x;
  const int w = t >> 6, lane = t & 63;
  const int lc = lane & 15, kg = lane >> 4;
  if (t < 128){ ssum[t] = 0.f; ssq[t] = 0.f; }
  const int m0 = blockIdx.x*64 + w*16;
  const int arow = m0 + lc;
  f32x4 acc[8];
  #pragma unroll
  for (int nf = 0; nf < 8; nf++){ acc[nf][0]=0.f; acc[nf][1]=0.f; acc[nf][2]=0.f; acc[nf][3]=0.f; }
  #pragma unroll
  for (int ks = 0; ks < 128; ks += 32){
    s16x8 a;
    if (arow < NN){
      f32x4 a0 = *(const f32x4*)(A + (size_t)arow*DD + ks + kg*8);
      f32x4 a1 = *(const f32x4*)(A + (size_t)arow*DD + ks + kg*8 + 4);
      a[0]=(short)f2bf(a0[0]); a[1]=(short)f2bf(a0[1]); a[2]=(short)f2bf(a0[2]); a[3]=(short)f2bf(a0[3]);
      a[4]=(short)f2bf(a1[0]); a[5]=(short)f2bf(a1[1]); a[6]=(short)f2bf(a1[2]); a[7]=(short)f2bf(a1[3]);
    } else {
      a[0]=0;a[1]=0;a[2]=0;a[3]=0;a[4]=0;a[5]=0;a[6]=0;a[7]=0;
    }
    #pragma unroll
    for (int nf = 0; nf < 8; nf++){
      s16x8 b = *(const s16x8*)(Wtwb + (nf*16 + lc)*DD + ks + kg*8);
      acc[nf] = __builtin_amdgcn_mfma_f32_16x16x32_bf16(a, b, acc[nf], 0, 0, 0);
    }
  }
  float ps[8], pq[8];
  #pragma unroll
  for (int nf = 0; nf < 8; nf++){
    ps[nf] = 0.f; pq[nf] = 0.f;
    const int col = nf*16 + lc;
    #pragma unroll
    for (int r = 0; r < 4; r++){
      int row = m0 + kg*4 + r;
      if (row < NN){
        float v = acc[nf][r];
        zb[(size_t)row*DD + col] = f2bf(v);
        ps[nf] += v; pq[nf] += v*v;
      }
    }
  }
  __syncthreads();
  #pragma unroll
  for (int nf = 0; nf < 8; nf++){
    atomicAdd(&ssum[nf*16 + lc], ps[nf]);
    atomicAdd(&ssq [nf*16 + lc], pq[nf]);
  }
  __syncthreads();
  if (t < 128){
    atomicAdd(&stats[ST_SUM2 + t], ssum[t]);
    atomicAdd(&stats[ST_SQ2  + t], ssq[t]);
  }
}

__global__ void sfin2(const float* gtw, const float* betw, float* __restrict__ stats){
  int c = threadIdx.x;
  if (c < 128){
    float mu = stats[ST_SUM2 + c] / (float)NN;
    float var = stats[ST_SQ2 + c] / (float)NN - mu*mu;
    float sc = gtw[c] * rsqrtf(var + EPSBN);
    stats[ST_SCALE2 + c] = sc;
    stats[ST_SHIFT2 + c] = betw[c] - mu*sc;
  }
}

// ---------------- x += relu(BN(zb)); refresh bf16 copy (vectorized) ----------------
__global__ void fuse_update(const unsigned short* __restrict__ zb,
                            const float* __restrict__ stats,
                            float* __restrict__ xcur, unsigned short* __restrict__ xb){
  const int tot = NN*DD/4;
  int stride = gridDim.x*blockDim.x;
  for (int i = blockIdx.x*blockDim.x + threadIdx.x; i < tot; i += stride){
    u16x4 z4 = ((const u16x4*)zb)[i];
    f32x4 x4 = ((const f32x4*)xcur)[i];
    const int c = (i*4) & 127;
    f32x4 o; u16x4 ob;
    #pragma unroll
    for (int j = 0; j < 4; j++){
      float hv = fmaxf(bf2f(z4[j])*stats[ST_SCALE2 + c + j] + stats[ST_SHIFT2 + c + j], 0.f);
      o[j] = x4[j] + hv;
      ob[j] = f2bf(o[j]);
    }
    ((f32x4*)xcur)[i] = o;
    ((u16x4*)xb)[i] = ob;
  }
}

extern "C" void kernel_launch(void* const* d_in, const int* in_sizes, int n_in,
                              void* d_out, int out_size, void* d_ws, size_t ws_size,
                              hipStream_t stream){
  const float* x    = (const float*)d_in[0];
  const int*   twi  = (const int*)d_in[1];
  const float* W_T  = (const float*)d_in[2];
  const float* W_M  = (const float*)d_in[3];
  const float* W_B  = (const float*)d_in[4];
  const float* W_1  = (const float*)d_in[5];
  const float* W_tw = (const float*)d_in[6];
  const float* g_T  = (const float*)d_in[8];
  const float* be_T = (const float*)d_in[9];
  const float* g_M  = (const float*)d_in[11];
  const float* be_M = (const float*)d_in[12];
  const float* g_B  = (const float*)d_in[14];
  const float* be_B = (const float*)d_in[15];
  const float* g_1  = (const float*)d_in[17];
  const float* be_1 = (const float*)d_in[18];
  const float* g_tw = (const float*)d_in[20];
  const float* be_tw= (const float*)d_in[21];
  float* xcur = (float*)d_out;

  char* ws = (char*)d_ws;
  size_t off = 0;
  auto take = [&](size_t b){ size_t o = off; off += (b + 255) & ~(size_t)255; return o; };
  float* stats = (float*)(ws + take(ST_TOTAL*4));
  unsigned short* Wcat = (unsigned short*)(ws + take(384*384*2));
  unsigned short* Wtwb = (unsigned short*)(ws + take(128*128*2));
  int* bsums  = (int*)(ws + take((size_t)3*SCB*4));
  int* cnt    = (int*)(ws + take((size_t)3*NN*4));
  int* startA = (int*)(ws + take((size_t)3*NN*4));
  int* cursor = (int*)(ws + take((size_t)3*NN*4));
  int* lists  = (int*)(ws + take((size_t)3*NE*4));
  float* sp   = (float*)(ws + take((size_t)NE*4));
  unsigned short* xb = (unsigned short*)(ws + take((size_t)NN*DD*2));
  float* macc = (float*)(ws + take((size_t)NN*DD*4));
  unsigned short* zb = (unsigned short*)(ws + take((size_t)NN*DD*2));
  unsigned short* h = (unsigned short*)(ws + take((size_t)NE*DD*2));  // plane 0
  size_t needA = off;
  take((size_t)2*NE*DD*2);  // planes 1,2 (contiguous: sizes are 256B-aligned)
  size_t needA2 = off;
  const bool planA2 = (ws_size >= needA2);
  const bool planA  = (ws_size >= needA);
  if (!planA) return;  // below minimum; avoid faulting

  hipMemsetAsync(cnt, 0, (size_t)3*NN*4, stream);
  hipMemsetAsync(cursor, 0, (size_t)3*NN*4, stream);
  init_x<<<1024, 256, 0, stream>>>(x, xcur, xb);
  csr_cnt<<<(NE+255)/256, 256, 0, stream>>>(twi, cnt);
  scan_bs<<<dim3(SCB, 3), 256, 0, stream>>>(cnt, bsums);
  scan_top<<<1, 64, 0, stream>>>(bsums);
  scan_fin<<<dim3(SCB, 3), 256, 0, stream>>>(cnt, bsums, startA);
  csr_fill<<<(NE+255)/256, 256, 0, stream>>>(twi, startA, cursor, lists);

  for (int l = 0; l < KL; l++){
    hipMemsetAsync(stats, 0, ST_TOTAL*4, stream);
    wprep<<<640, 256, 0, stream>>>(W_T + (size_t)l*DD*D3, W_M + (size_t)l*DD*D3,
                                   W_B + (size_t)l*DD*D3, W_tw + (size_t)l*DD*DD,
                                   Wcat, Wtwb);
    const float* gs[3]  = {g_T  + (size_t)l*DD, g_M  + (size_t)l*DD, g_B  + (size_t)l*DD};
    const float* bes[3] = {be_T + (size_t)l*DD, be_M + (size_t)l*DD, be_B + (size_t)l*DD};
    const float* W1l = W_1 + (size_t)l*D3;

    if (planA2){
      g1k<1><<<EB, 256, 0, stream>>>(xb, Wcat, W1l, twi, h, sp, stats, -1);
      sfin_all<<<1, 512, 0, stream>>>(gs[0], bes[0], gs[1], bes[1], gs[2], bes[2],
                                      g_1 + l, be_1 + l, stats);
      sm_max<<<1024, 256, 0, stream>>>(sp, stats);
      sm_sum<<<1024, 256, 0, stream>>>(sp, stats);
      sm_att<<<1024, 256, 0, stream>>>(sp, stats);
      scat<1><<<(NN+3)/4, 256, 0, stream>>>(h, sp, cnt, startA, lists, stats, macc, -1);
    } else {
      hipMemsetAsync(macc, 0, (size_t)NN*DD*4, stream);
      // part 0 (+score), then softmax, then interleave remaining parts
      g1k<0><<<EB, 256, 0, stream>>>(xb, Wcat, W1l, twi, h, sp, stats, 0);
      sfin_score<<<1, 64, 0, stream>>>(g_1 + l, be_1 + l, stats);
      sm_max<<<1024, 256, 0, stream>>>(sp, stats);
      sm_sum<<<1024, 256, 0, stream>>>(sp, stats);
      sm_att<<<1024, 256, 0, stream>>>(sp, stats);
      sfin_cols<<<1, 128, 0, stream>>>(gs[0], bes[0], stats, 0);
      scat<0><<<(NN+3)/4, 256, 0, stream>>>(h, sp, cnt, startA, lists, stats, macc, 0);
      for (int p = 1; p < 3; p++){
        g1k<0><<<EB, 256, 0, stream>>>(xb, Wcat, W1l, twi, h, sp, stats, p);
        sfin_cols<<<1, 128, 0, stream>>>(gs[p], bes[p], stats, p);
        scat<0><<<(NN+3)/4, 256, 0, stream>>>(h, sp, cnt, startA, lists, stats, macc, p);
      }
    }

    g2_gemm<<<(NN+63)/64, 256, 0, stream>>>(macc, Wtwb, zb, stats);
    sfin2<<<1, 128, 0, stream>>>(g_tw + (size_t)l*DD, be_tw + (size_t)l*DD, stats);
    fuse_update<<<1024, 256, 0, stream>>>(zb, stats, xcur, xb);
  }
}

// Round 6
// 3256.489 us; speedup vs baseline: 1.2900x; 1.0056x over previous
//
#include <hip/hip_runtime.h>

#define NN 100000
#define NE 400000
#define DD 128
#define D3 384
#define KL 2
#define EPSBN 1e-5f
#define EB (NE/64)
#define SCB ((NN + 1023) / 1024)

typedef __attribute__((ext_vector_type(8))) short s16x8;
typedef __attribute__((ext_vector_type(4))) float f32x4;
typedef __attribute__((ext_vector_type(4))) unsigned short u16x4;

#define ST_SUM    0      // [384]
#define ST_SQ     384    // [384]
#define ST_SCALE  768    // [384]
#define ST_SHIFT  1152   // [384]
#define ST_SUM1   1536
#define ST_SQ1    1537
#define ST_MAX    1538
#define ST_SEXP   1539
#define ST_SCALE1 1540
#define ST_SHIFT1 1541
#define ST_SUM2   1542   // [128]
#define ST_SQ2    1670   // [128]
#define ST_SCALE2 1798   // [128]
#define ST_SHIFT2 1926   // [128]
#define ST_TOTAL  2054

__device__ __forceinline__ float bf2f(unsigned short u){
  return __uint_as_float(((unsigned int)u) << 16);
}
__device__ __forceinline__ unsigned short f2bf(float f){
  unsigned int x = __float_as_uint(f);
  x = x + 0x7FFFu + ((x >> 16) & 1u);
  return (unsigned short)(x >> 16);
}

// ---------------- init: x -> xcur (f32) + xb (bf16), vectorized ----------------
__global__ void init_x(const float* __restrict__ x, float* __restrict__ xcur,
                       unsigned short* __restrict__ xb){
  const int tot = NN*DD/4;
  int stride = gridDim.x * blockDim.x;
  for (int i = blockIdx.x*blockDim.x + threadIdx.x; i < tot; i += stride){
    f32x4 v = ((const f32x4*)x)[i];
    ((f32x4*)xcur)[i] = v;
    u16x4 o; o[0]=f2bf(v[0]); o[1]=f2bf(v[1]); o[2]=f2bf(v[2]); o[3]=f2bf(v[3]);
    ((u16x4*)xb)[i] = o;
  }
}

// ---------------- weight prep (per layer) ----------------
__global__ void wprep(const float* __restrict__ WT, const float* __restrict__ WM,
                      const float* __restrict__ WB, const float* __restrict__ Wtw,
                      unsigned short* __restrict__ Wcat, unsigned short* __restrict__ Wtwb){
  int stride = gridDim.x * blockDim.x;
  int tid = blockIdx.x*blockDim.x + threadIdx.x;
  for (int i = tid; i < 384*384; i += stride){
    int n = i / 384, k = i - n*384;
    float v;
    if (n < 128)      v = WT[n*384 + k];
    else if (n < 256) v = WM[(n-128)*384 + k];
    else              v = WB[(n-256)*384 + k];
    Wcat[i] = f2bf(v);
  }
  for (int i = tid; i < 128*128; i += stride) Wtwb[i] = f2bf(Wtw[i]);
}

// ---------------- CSR build ----------------
__global__ void csr_cnt(const int* __restrict__ twi, int* __restrict__ cnt){
  int e = blockIdx.x*blockDim.x + threadIdx.x;
  if (e < NE){
    atomicAdd(&cnt[0*NN + twi[0*NE + e]], 1);
    atomicAdd(&cnt[1*NN + twi[1*NE + e]], 1);
    atomicAdd(&cnt[2*NN + twi[2*NE + e]], 1);
  }
}

__global__ void scan_bs(const int* __restrict__ cnt, int* __restrict__ bsums){
  const int p = blockIdx.y, b = blockIdx.x, t = threadIdx.x;
  const int base = b * 1024;
  int s = 0;
  #pragma unroll
  for (int j = 0; j < 4; j++){
    int i = base + t + j*256;
    if (i < NN) s += cnt[p*NN + i];
  }
  __shared__ int red[256];
  red[t] = s; __syncthreads();
  #pragma unroll
  for (int o = 128; o; o >>= 1){
    if (t < o) red[t] += red[t+o];
    __syncthreads();
  }
  if (t == 0) bsums[p*SCB + b] = red[0];
}

__global__ void scan_top(int* __restrict__ bsums){
  const int p = threadIdx.x;
  if (p < 3){
    int run = 0;
    for (int i = 0; i < SCB; i++){ int v = bsums[p*SCB + i]; bsums[p*SCB + i] = run; run += v; }
  }
}

__global__ void scan_fin(const int* __restrict__ cnt, const int* __restrict__ bsums,
                         int* __restrict__ start){
  const int p = blockIdx.y, b = blockIdx.x, t = threadIdx.x;
  const int base = b * 1024;
  int v[4]; int s = 0;
  #pragma unroll
  for (int j = 0; j < 4; j++){
    int i = base + t*4 + j;
    v[j] = (i < NN) ? cnt[p*NN + i] : 0;
    s += v[j];
  }
  __shared__ int red[256];
  red[t] = s; __syncthreads();
  #pragma unroll
  for (int o = 1; o < 256; o <<= 1){
    int other = (t >= o) ? red[t - o] : 0;
    __syncthreads();
    red[t] += other;
    __syncthreads();
  }
  int ex = red[t] - s + bsums[p*SCB + b];
  #pragma unroll
  for (int j = 0; j < 4; j++){
    int i = base + t*4 + j;
    if (i < NN) start[p*NN + i] = ex;
    ex += v[j];
  }
}

__global__ void csr_fill(const int* __restrict__ twi, const int* __restrict__ start,
                         int* __restrict__ cursor, int* __restrict__ lists){
  int e = blockIdx.x*blockDim.x + threadIdx.x;
  if (e < NE){
    #pragma unroll
    for (int p = 0; p < 3; p++){
      int n = twi[p*NE + e];
      int pos = atomicAdd(&cursor[p*NN + n], 1);
      lists[(size_t)p*NE + start[p*NN + n] + pos] = e;
    }
  }
}

// ------------- gathered GEMM: NP parts per dispatch, pinned A-prefetch -----------
// Epilogue identical to round-4 (LDS repack, direct h writes, LDS stat atomics).
template<int NP, int DOSCORE>
__launch_bounds__(256)
__global__ void g1k(const unsigned short* __restrict__ xb,
                    const unsigned short* __restrict__ Wcat,
                    const float* __restrict__ W1,
                    const int* __restrict__ twi,
                    unsigned short* __restrict__ h,
                    float* __restrict__ sp,
                    float* __restrict__ stats,
                    int p0){
  __shared__ float lt[4][16][128];
  __shared__ float ssum[128], ssq[128];
  __shared__ float s1s[4], s1q[4];
  const int t = threadIdx.x;
  const int w = t >> 6, lane = t & 63;
  const int lc = lane & 15, kg = lane >> 4;
  const int eBase = blockIdx.x * 64;
  const int edge = eBase + w*16 + lc;
  const int nd0 = twi[edge], nd1 = twi[NE + edge], nd2 = twi[2*NE + edge];

  // ---- prefetch ALL 12 A-gather fragments; sched_barrier pins them up-front ----
  s16x8 areg[12];
  #pragma unroll
  for (int ks = 0; ks < 12; ks++){
    const int nd = (ks < 4) ? nd0 : ((ks < 8) ? nd1 : nd2);
    areg[ks] = *(const s16x8*)(xb + (size_t)nd*DD + (ks & 3)*32 + kg*8);
  }
  __builtin_amdgcn_sched_barrier(0);

  if (DOSCORE){
    float sa = 0.f;
    #pragma unroll
    for (int ks = 0; ks < 12; ks++){
      const float* wp = W1 + ks*32 + kg*8;
      f32x4 w0 = *(const f32x4*)wp;
      f32x4 w1v = *(const f32x4*)(wp + 4);
      #pragma unroll
      for (int j = 0; j < 4; j++) sa += bf2f((unsigned short)areg[ks][j])   * w0[j];
      #pragma unroll
      for (int j = 0; j < 4; j++) sa += bf2f((unsigned short)areg[ks][4+j]) * w1v[j];
    }
    sa += __shfl_xor(sa, 16);
    sa += __shfl_xor(sa, 32);
    if (lane < 16) sp[edge] = sa;
    float sv = (lane < 16) ? sa : 0.f;
    float qv = sv*sv;
    #pragma unroll
    for (int o = 8; o; o >>= 1){ sv += __shfl_xor(sv, o); qv += __shfl_xor(qv, o); }
    if (lane == 0){ s1s[w] = sv; s1q[w] = qv; }
    __syncthreads();
    if (t == 0){
      atomicAdd(&stats[ST_SUM1], s1s[0]+s1s[1]+s1s[2]+s1s[3]);
      atomicAdd(&stats[ST_SQ1],  s1q[0]+s1q[1]+s1q[2]+s1q[3]);
    }
  }

  #pragma unroll 1
  for (int pp = 0; pp < NP; pp++){
    const int p = p0 + pp;
    if (t < 128){ ssum[t] = 0.f; ssq[t] = 0.f; }
    __syncthreads();

    f32x4 acc[8];
    #pragma unroll
    for (int nf = 0; nf < 8; nf++){ acc[nf][0]=0.f; acc[nf][1]=0.f; acc[nf][2]=0.f; acc[nf][3]=0.f; }

    const unsigned short* wb = Wcat + (size_t)(p*128 + lc)*D3 + kg*8;
    #pragma unroll
    for (int ks = 0; ks < 12; ks++){
      #pragma unroll
      for (int nf = 0; nf < 8; nf++){
        s16x8 b = *(const s16x8*)(wb + nf*16*D3 + ks*32);
        acc[nf] = __builtin_amdgcn_mfma_f32_16x16x32_bf16(areg[ks], b, acc[nf], 0, 0, 0);
      }
    }

    // wave-local repack (C frag: row=(lane>>4)*4+r, col=lane&15)
    #pragma unroll
    for (int nf = 0; nf < 8; nf++)
      #pragma unroll
      for (int r = 0; r < 4; r++)
        lt[w][kg*4 + r][nf*16 + lc] = acc[nf][r];

    unsigned short* hp = h + (size_t)pp*NE*DD;
    const int rl = lane >> 5, cg = lane & 31;
    float ps0=0,ps1=0,ps2=0,ps3=0, pq0=0,pq1=0,pq2=0,pq3=0;
    #pragma unroll
    for (int it = 0; it < 8; it++){
      const int row = it*2 + rl;
      f32x4 v = *(const f32x4*)&lt[w][row][cg*4];
      u16x4 o;
      o[0]=f2bf(v[0]); o[1]=f2bf(v[1]); o[2]=f2bf(v[2]); o[3]=f2bf(v[3]);
      *(u16x4*)(hp + (size_t)(eBase + w*16 + row)*DD + cg*4) = o;
      ps0 += v[0]; ps1 += v[1]; ps2 += v[2]; ps3 += v[3];
      pq0 += v[0]*v[0]; pq1 += v[1]*v[1]; pq2 += v[2]*v[2]; pq3 += v[3]*v[3];
    }
    ps0 += __shfl_xor(ps0, 32); ps1 += __shfl_xor(ps1, 32);
    ps2 += __shfl_xor(ps2, 32); ps3 += __shfl_xor(ps3, 32);
    pq0 += __shfl_xor(pq0, 32); pq1 += __shfl_xor(pq1, 32);
    pq2 += __shfl_xor(pq2, 32); pq3 += __shfl_xor(pq3, 32);
    if (lane < 32){
      atomicAdd(&ssum[cg*4+0], ps0); atomicAdd(&ssum[cg*4+1], ps1);
      atomicAdd(&ssum[cg*4+2], ps2); atomicAdd(&ssum[cg*4+3], ps3);
      atomicAdd(&ssq [cg*4+0], pq0); atomicAdd(&ssq [cg*4+1], pq1);
      atomicAdd(&ssq [cg*4+2], pq2); atomicAdd(&ssq [cg*4+3], pq3);
    }
    __syncthreads();
    if (t < 128){
      atomicAdd(&stats[ST_SUM + p*128 + t], ssum[t]);
      atomicAdd(&stats[ST_SQ  + p*128 + t], ssq[t]);
    }
  }
}

// ---------------- BN finalize ----------------
__global__ void sfin_score(const float* g1, const float* be1, float* __restrict__ stats){
  if (threadIdx.x == 0){
    float mu = stats[ST_SUM1] / (float)NE;
    float var = stats[ST_SQ1] / (float)NE - mu*mu;
    float sc = g1[0] * rsqrtf(var + EPSBN);
    stats[ST_SCALE1] = sc;
    stats[ST_SHIFT1] = be1[0] - mu*sc;
  }
}

__global__ void sfin_cols(const float* g, const float* be, float* __restrict__ stats, int part){
  int t = threadIdx.x;
  if (t < 128){
    int idx = part*128 + t;
    float mu = stats[ST_SUM + idx] / (float)NE;
    float var = stats[ST_SQ + idx] / (float)NE - mu*mu;
    float sc = g[t] * rsqrtf(var + EPSBN);
    stats[ST_SCALE + idx] = sc;
    stats[ST_SHIFT + idx] = be[t] - mu*sc;
  }
}

__global__ void sfin_all(const float* gT, const float* beT, const float* gM, const float* beM,
                         const float* gB, const float* beB, const float* g1, const float* be1,
                         float* __restrict__ stats){
  int t = threadIdx.x;
  if (t < 384){
    float mu = stats[ST_SUM + t] / (float)NE;
    float var = stats[ST_SQ + t] / (float)NE - mu*mu;
    float g, be;
    if (t < 128)      { g = gT[t];     be = beT[t]; }
    else if (t < 256) { g = gM[t-128]; be = beM[t-128]; }
    else              { g = gB[t-256]; be = beB[t-256]; }
    float sc = g * rsqrtf(var + EPSBN);
    stats[ST_SCALE + t] = sc;
    stats[ST_SHIFT + t] = be - mu*sc;
  } else if (t == 384){
    float mu = stats[ST_SUM1] / (float)NE;
    float var = stats[ST_SQ1] / (float)NE - mu*mu;
    float sc = g1[0] * rsqrtf(var + EPSBN);
    stats[ST_SCALE1] = sc;
    stats[ST_SHIFT1] = be1[0] - mu*sc;
  }
}

// ---------------- softmax: max, sum, att in place ----------------
__global__ void sm_max(float* __restrict__ sp, float* __restrict__ stats){
  const float sc = stats[ST_SCALE1], sh = stats[ST_SHIFT1];
  float lmax = 0.f;
  int stride = gridDim.x*blockDim.x;
  for (int i = blockIdx.x*blockDim.x + threadIdx.x; i < NE; i += stride){
    float s = fmaxf(sp[i]*sc + sh, 0.f);
    sp[i] = s;
    lmax = fmaxf(lmax, s);
  }
  #pragma unroll
  for (int o = 32; o; o >>= 1) lmax = fmaxf(lmax, __shfl_xor(lmax, o));
  __shared__ float red[4];
  if ((threadIdx.x & 63) == 0) red[threadIdx.x >> 6] = lmax;
  __syncthreads();
  if (threadIdx.x == 0){
    float m = fmaxf(fmaxf(red[0], red[1]), fmaxf(red[2], red[3]));
    atomicMax((unsigned int*)&stats[ST_MAX], __float_as_uint(m));
  }
}

__global__ void sm_sum(const float* __restrict__ sp, float* __restrict__ stats){
  const float mx = __uint_as_float(((const unsigned int*)stats)[ST_MAX]);
  float ls = 0.f;
  int stride = gridDim.x*blockDim.x;
  for (int i = blockIdx.x*blockDim.x + threadIdx.x; i < NE; i += stride)
    ls += __expf(sp[i] - mx);
  #pragma unroll
  for (int o = 32; o; o >>= 1) ls += __shfl_xor(ls, o);
  __shared__ float red[4];
  if ((threadIdx.x & 63) == 0) red[threadIdx.x >> 6] = ls;
  __syncthreads();
  if (threadIdx.x == 0)
    atomicAdd(&stats[ST_SEXP], red[0] + red[1] + red[2] + red[3]);
}

__global__ void sm_att(float* __restrict__ sp, const float* __restrict__ stats){
  const float mx = __uint_as_float(((const unsigned int*)stats)[ST_MAX]);
  const float invZ = 1.0f / stats[ST_SEXP];
  int stride = gridDim.x*blockDim.x;
  for (int i = blockIdx.x*blockDim.x + threadIdx.x; i < NE; i += stride)
    sp[i] = __expf(sp[i] - mx) * invZ;
}

// -------- node-centric scatter-mean, NP parts per call, f32 macc += --------
template<int NP>
__launch_bounds__(256)
__global__ void scat(const unsigned short* __restrict__ h,
                     const float* __restrict__ att,
                     const int* __restrict__ cnt, const int* __restrict__ start,
                     const int* __restrict__ lists,
                     const float* __restrict__ stats,
                     float* __restrict__ macc, int p0){
  const int w = threadIdx.x >> 6, lane = threadIdx.x & 63;
  const int n = blockIdx.x*4 + w;
  if (n >= NN) return;
  float a0 = 0.f, a1 = 0.f;
  for (int q = 0; q < NP; q++){
    const int p = p0 + q;
    const unsigned short* hq = h + (size_t)q*NE*DD;
    const float sc0 = stats[ST_SCALE + p*128 + lane];
    const float sh0 = stats[ST_SHIFT + p*128 + lane];
    const float sc1 = stats[ST_SCALE + p*128 + 64 + lane];
    const float sh1 = stats[ST_SHIFT + p*128 + 64 + lane];
    const int cs = start[p*NN + n];
    const int c  = cnt[p*NN + n];
    float p0a = 0.f, p1a = 0.f;
    for (int j = 0; j < c; j++){
      const int e = lists[(size_t)p*NE + cs + j];
      const float av = att[e];
      const float v0 = bf2f(hq[(size_t)e*DD + lane]);
      const float v1 = bf2f(hq[(size_t)e*DD + 64 + lane]);
      p0a += av * fmaxf(v0*sc0 + sh0, 0.f);
      p1a += av * fmaxf(v1*sc1 + sh1, 0.f);
    }
    if (c > 0){ float ic = 1.f / (float)c; a0 += p0a*ic; a1 += p1a*ic; }
  }
  macc[(size_t)n*DD + lane]      += a0;
  macc[(size_t)n*DD + 64 + lane] += a1;
}

// ---------------- zb = bf16(macc @ Wtw^T), fused col stats ----------------
__launch_bounds__(256)
__global__ void g2_gemm(const float* __restrict__ A,
                        const unsigned short* __restrict__ Wtwb,
                        unsigned short* __restrict__ zb,
                        float* __restrict__ stats){
  __shared__ float ssum[128], ssq[128];
  const int t = threadIdx.x;
  const int w = t >> 6, lane = t & 63;
  const int lc = lane & 15, kg = lane >> 4;
  if (t < 128){ ssum[t] = 0.f; ssq[t] = 0.f; }
  const int m0 = blockIdx.x*64 + w*16;
  const int arow = m0 + lc;
  f32x4 acc[8];
  #pragma unroll
  for (int nf = 0; nf < 8; nf++){ acc[nf][0]=0.f; acc[nf][1]=0.f; acc[nf][2]=0.f; acc[nf][3]=0.f; }
  #pragma unroll
  for (int ks = 0; ks < 128; ks += 32){
    s16x8 a;
    if (arow < NN){
      f32x4 a0 = *(const f32x4*)(A + (size_t)arow*DD + ks + kg*8);
      f32x4 a1 = *(const f32x4*)(A + (size_t)arow*DD + ks + kg*8 + 4);
      a[0]=(short)f2bf(a0[0]); a[1]=(short)f2bf(a0[1]); a[2]=(short)f2bf(a0[2]); a[3]=(short)f2bf(a0[3]);
      a[4]=(short)f2bf(a1[0]); a[5]=(short)f2bf(a1[1]); a[6]=(short)f2bf(a1[2]); a[7]=(short)f2bf(a1[3]);
    } else {
      a[0]=0;a[1]=0;a[2]=0;a[3]=0;a[4]=0;a[5]=0;a[6]=0;a[7]=0;
    }
    #pragma unroll
    for (int nf = 0; nf < 8; nf++){
      s16x8 b = *(const s16x8*)(Wtwb + (nf*16 + lc)*DD + ks + kg*8);
      acc[nf] = __builtin_amdgcn_mfma_f32_16x16x32_bf16(a, b, acc[nf], 0, 0, 0);
    }
  }
  float ps[8], pq[8];
  #pragma unroll
  for (int nf = 0; nf < 8; nf++){
    ps[nf] = 0.f; pq[nf] = 0.f;
    const int col = nf*16 + lc;
    #pragma unroll
    for (int r = 0; r < 4; r++){
      int row = m0 + kg*4 + r;
      if (row < NN){
        float v = acc[nf][r];
        zb[(size_t)row*DD + col] = f2bf(v);
        ps[nf] += v; pq[nf] += v*v;
      }
    }
  }
  __syncthreads();
  #pragma unroll
  for (int nf = 0; nf < 8; nf++){
    atomicAdd(&ssum[nf*16 + lc], ps[nf]);
    atomicAdd(&ssq [nf*16 + lc], pq[nf]);
  }
  __syncthreads();
  if (t < 128){
    atomicAdd(&stats[ST_SUM2 + t], ssum[t]);
    atomicAdd(&stats[ST_SQ2  + t], ssq[t]);
  }
}

__global__ void sfin2(const float* gtw, const float* betw, float* __restrict__ stats){
  int c = threadIdx.x;
  if (c < 128){
    float mu = stats[ST_SUM2 + c] / (float)NN;
    float var = stats[ST_SQ2 + c] / (float)NN - mu*mu;
    float sc = gtw[c] * rsqrtf(var + EPSBN);
    stats[ST_SCALE2 + c] = sc;
    stats[ST_SHIFT2 + c] = betw[c] - mu*sc;
  }
}

// ---------------- x += relu(BN(zb)); refresh bf16 copy (vectorized) ----------------
__global__ void fuse_update(const unsigned short* __restrict__ zb,
                            const float* __restrict__ stats,
                            float* __restrict__ xcur, unsigned short* __restrict__ xb){
  const int tot = NN*DD/4;
  int stride = gridDim.x*blockDim.x;
  for (int i = blockIdx.x*blockDim.x + threadIdx.x; i < tot; i += stride){
    u16x4 z4 = ((const u16x4*)zb)[i];
    f32x4 x4 = ((const f32x4*)xcur)[i];
    const int c = (i*4) & 127;
    f32x4 o; u16x4 ob;
    #pragma unroll
    for (int j = 0; j < 4; j++){
      float hv = fmaxf(bf2f(z4[j])*stats[ST_SCALE2 + c + j] + stats[ST_SHIFT2 + c + j], 0.f);
      o[j] = x4[j] + hv;
      ob[j] = f2bf(o[j]);
    }
    ((f32x4*)xcur)[i] = o;
    ((u16x4*)xb)[i] = ob;
  }
}

extern "C" void kernel_launch(void* const* d_in, const int* in_sizes, int n_in,
                              void* d_out, int out_size, void* d_ws, size_t ws_size,
                              hipStream_t stream){
  const float* x    = (const float*)d_in[0];
  const int*   twi  = (const int*)d_in[1];
  const float* W_T  = (const float*)d_in[2];
  const float* W_M  = (const float*)d_in[3];
  const float* W_B  = (const float*)d_in[4];
  const float* W_1  = (const float*)d_in[5];
  const float* W_tw = (const float*)d_in[6];
  const float* g_T  = (const float*)d_in[8];
  const float* be_T = (const float*)d_in[9];
  const float* g_M  = (const float*)d_in[11];
  const float* be_M = (const float*)d_in[12];
  const float* g_B  = (const float*)d_in[14];
  const float* be_B = (const float*)d_in[15];
  const float* g_1  = (const float*)d_in[17];
  const float* be_1 = (const float*)d_in[18];
  const float* g_tw = (const float*)d_in[20];
  const float* be_tw= (const float*)d_in[21];
  float* xcur = (float*)d_out;

  char* ws = (char*)d_ws;
  size_t off = 0;
  auto take = [&](size_t b){ size_t o = off; off += (b + 255) & ~(size_t)255; return o; };
  float* stats = (float*)(ws + take(ST_TOTAL*4));
  unsigned short* Wcat = (unsigned short*)(ws + take(384*384*2));
  unsigned short* Wtwb = (unsigned short*)(ws + take(128*128*2));
  int* bsums  = (int*)(ws + take((size_t)3*SCB*4));
  int* cnt    = (int*)(ws + take((size_t)3*NN*4));
  int* startA = (int*)(ws + take((size_t)3*NN*4));
  int* cursor = (int*)(ws + take((size_t)3*NN*4));
  int* lists  = (int*)(ws + take((size_t)3*NE*4));
  float* sp   = (float*)(ws + take((size_t)NE*4));
  unsigned short* xb = (unsigned short*)(ws + take((size_t)NN*DD*2));
  float* macc = (float*)(ws + take((size_t)NN*DD*4));
  unsigned short* zb = (unsigned short*)(ws + take((size_t)NN*DD*2));
  size_t hoff = off;
  unsigned short* h = (unsigned short*)(ws + hoff);
  const size_t plane = (size_t)NE*DD*2;
  int P = 0;
  if (ws_size > hoff)
    P = (int)((ws_size - hoff) / plane);
  if (P > 3) P = 3;
  if (P < 1) return;  // cannot run; avoid faulting

  hipMemsetAsync(cnt, 0, (size_t)3*NN*4, stream);
  hipMemsetAsync(cursor, 0, (size_t)3*NN*4, stream);
  init_x<<<1024, 256, 0, stream>>>(x, xcur, xb);
  csr_cnt<<<(NE+255)/256, 256, 0, stream>>>(twi, cnt);
  scan_bs<<<dim3(SCB, 3), 256, 0, stream>>>(cnt, bsums);
  scan_top<<<1, 64, 0, stream>>>(bsums);
  scan_fin<<<dim3(SCB, 3), 256, 0, stream>>>(cnt, bsums, startA);
  csr_fill<<<(NE+255)/256, 256, 0, stream>>>(twi, startA, cursor, lists);

  for (int l = 0; l < KL; l++){
    hipMemsetAsync(stats, 0, ST_TOTAL*4, stream);
    hipMemsetAsync(macc, 0, (size_t)NN*DD*4, stream);
    wprep<<<640, 256, 0, stream>>>(W_T + (size_t)l*DD*D3, W_M + (size_t)l*DD*D3,
                                   W_B + (size_t)l*DD*D3, W_tw + (size_t)l*DD*DD,
                                   Wcat, Wtwb);
    const float* gs[3]  = {g_T  + (size_t)l*DD, g_M  + (size_t)l*DD, g_B  + (size_t)l*DD};
    const float* bes[3] = {be_T + (size_t)l*DD, be_M + (size_t)l*DD, be_B + (size_t)l*DD};
    const float* W1l = W_1 + (size_t)l*D3;

    if (P >= 3){
      g1k<3,1><<<EB, 256, 0, stream>>>(xb, Wcat, W1l, twi, h, sp, stats, 0);
      sfin_all<<<1, 512, 0, stream>>>(gs[0], bes[0], gs[1], bes[1], gs[2], bes[2],
                                      g_1 + l, be_1 + l, stats);
      sm_max<<<1024, 256, 0, stream>>>(sp, stats);
      sm_sum<<<1024, 256, 0, stream>>>(sp, stats);
      sm_att<<<1024, 256, 0, stream>>>(sp, stats);
      scat<3><<<(NN+3)/4, 256, 0, stream>>>(h, sp, cnt, startA, lists, stats, macc, 0);
    } else if (P == 2){
      g1k<2,1><<<EB, 256, 0, stream>>>(xb, Wcat, W1l, twi, h, sp, stats, 0);
      sfin_score<<<1, 64, 0, stream>>>(g_1 + l, be_1 + l, stats);
      sm_max<<<1024, 256, 0, stream>>>(sp, stats);
      sm_sum<<<1024, 256, 0, stream>>>(sp, stats);
      sm_att<<<1024, 256, 0, stream>>>(sp, stats);
      sfin_cols<<<1, 128, 0, stream>>>(gs[0], bes[0], stats, 0);
      sfin_cols<<<1, 128, 0, stream>>>(gs[1], bes[1], stats, 1);
      scat<2><<<(NN+3)/4, 256, 0, stream>>>(h, sp, cnt, startA, lists, stats, macc, 0);
      g1k<1,0><<<EB, 256, 0, stream>>>(xb, Wcat, W1l, twi, h, sp, stats, 2);
      sfin_cols<<<1, 128, 0, stream>>>(gs[2], bes[2], stats, 2);
      scat<1><<<(NN+3)/4, 256, 0, stream>>>(h, sp, cnt, startA, lists, stats, macc, 2);
    } else {
      g1k<1,1><<<EB, 256, 0, stream>>>(xb, Wcat, W1l, twi, h, sp, stats, 0);
      sfin_score<<<1, 64, 0, stream>>>(g_1 + l, be_1 + l, stats);
      sm_max<<<1024, 256, 0, stream>>>(sp, stats);
      sm_sum<<<1024, 256, 0, stream>>>(sp, stats);
      sm_att<<<1024, 256, 0, stream>>>(sp, stats);
      sfin_cols<<<1, 128, 0, stream>>>(gs[0], bes[0], stats, 0);
      scat<1><<<(NN+3)/4, 256, 0, stream>>>(h, sp, cnt, startA, lists, stats, macc, 0);
      for (int p = 1; p < 3; p++){
        g1k<1,0><<<EB, 256, 0, stream>>>(xb, Wcat, W1l, twi, h, sp, stats, p);
        sfin_cols<<<1, 128, 0, stream>>>(gs[p], bes[p], stats, p);
        scat<1><<<(NN+3)/4, 256, 0, stream>>>(h, sp, cnt, startA, lists, stats, macc, p);
      }
    }

    g2_gemm<<<(NN+63)/64, 256, 0, stream>>>(macc, Wtwb, zb, stats);
    sfin2<<<1, 128, 0, stream>>>(g_tw + (size_t)l*DD, be_tw + (size_t)l*DD, stats);
    fuse_update<<<1024, 256, 0, stream>>>(zb, stats, xcur, xb);
  }
}

// Round 7
// 3072.956 us; speedup vs baseline: 1.3671x; 1.0597x over previous
//
#include <hip/hip_runtime.h>

#define NN 100000
#define NE 400000
#define DD 128
#define D3 384
#define KL 2
#define EPSBN 1e-5f
#define EB (NE/64)
#define SCB ((NN + 1023) / 1024)

typedef __attribute__((ext_vector_type(8))) short s16x8;
typedef __attribute__((ext_vector_type(4))) float f32x4;
typedef __attribute__((ext_vector_type(4))) unsigned short u16x4;

#define ST_SUM    0      // [384]
#define ST_SQ     384    // [384]
#define ST_SCALE  768    // [384]
#define ST_SHIFT  1152   // [384]
#define ST_SUM1   1536
#define ST_SQ1    1537
#define ST_MAX    1538
#define ST_SEXP   1539
#define ST_SCALE1 1540
#define ST_SHIFT1 1541
#define ST_SUM2   1542   // [128]
#define ST_SQ2    1670   // [128]
#define ST_SCALE2 1798   // [128]
#define ST_SHIFT2 1926   // [128]
#define ST_TOTAL  2054

__device__ __forceinline__ float bf2f(unsigned short u){
  return __uint_as_float(((unsigned int)u) << 16);
}
__device__ __forceinline__ unsigned short f2bf(float f){
  unsigned int x = __float_as_uint(f);
  x = x + 0x7FFFu + ((x >> 16) & 1u);
  return (unsigned short)(x >> 16);
}

// ---------------- init: x -> xcur (f32) + xb (bf16), vectorized ----------------
__global__ void init_x(const float* __restrict__ x, float* __restrict__ xcur,
                       unsigned short* __restrict__ xb){
  const int tot = NN*DD/4;
  int stride = gridDim.x * blockDim.x;
  for (int i = blockIdx.x*blockDim.x + threadIdx.x; i < tot; i += stride){
    f32x4 v = ((const f32x4*)x)[i];
    ((f32x4*)xcur)[i] = v;
    u16x4 o; o[0]=f2bf(v[0]); o[1]=f2bf(v[1]); o[2]=f2bf(v[2]); o[3]=f2bf(v[3]);
    ((u16x4*)xb)[i] = o;
  }
}

// ---------------- weight prep (per layer) ----------------
__global__ void wprep(const float* __restrict__ WT, const float* __restrict__ WM,
                      const float* __restrict__ WB, const float* __restrict__ Wtw,
                      unsigned short* __restrict__ Wcat, unsigned short* __restrict__ Wtwb){
  int stride = gridDim.x * blockDim.x;
  int tid = blockIdx.x*blockDim.x + threadIdx.x;
  for (int i = tid; i < 384*384; i += stride){
    int n = i / 384, k = i - n*384;
    float v;
    if (n < 128)      v = WT[n*384 + k];
    else if (n < 256) v = WM[(n-128)*384 + k];
    else              v = WB[(n-256)*384 + k];
    Wcat[i] = f2bf(v);
  }
  for (int i = tid; i < 128*128; i += stride) Wtwb[i] = f2bf(Wtw[i]);
}

// ---------------- CSR build ----------------
__global__ void csr_cnt(const int* __restrict__ twi, int* __restrict__ cnt){
  int e = blockIdx.x*blockDim.x + threadIdx.x;
  if (e < NE){
    atomicAdd(&cnt[0*NN + twi[0*NE + e]], 1);
    atomicAdd(&cnt[1*NN + twi[1*NE + e]], 1);
    atomicAdd(&cnt[2*NN + twi[2*NE + e]], 1);
  }
}

__global__ void scan_bs(const int* __restrict__ cnt, int* __restrict__ bsums){
  const int p = blockIdx.y, b = blockIdx.x, t = threadIdx.x;
  const int base = b * 1024;
  int s = 0;
  #pragma unroll
  for (int j = 0; j < 4; j++){
    int i = base + t + j*256;
    if (i < NN) s += cnt[p*NN + i];
  }
  __shared__ int red[256];
  red[t] = s; __syncthreads();
  #pragma unroll
  for (int o = 128; o; o >>= 1){
    if (t < o) red[t] += red[t+o];
    __syncthreads();
  }
  if (t == 0) bsums[p*SCB + b] = red[0];
}

__global__ void scan_top(int* __restrict__ bsums){
  const int p = threadIdx.x;
  if (p < 3){
    int run = 0;
    for (int i = 0; i < SCB; i++){ int v = bsums[p*SCB + i]; bsums[p*SCB + i] = run; run += v; }
  }
}

__global__ void scan_fin(const int* __restrict__ cnt, const int* __restrict__ bsums,
                         int* __restrict__ start){
  const int p = blockIdx.y, b = blockIdx.x, t = threadIdx.x;
  const int base = b * 1024;
  int v[4]; int s = 0;
  #pragma unroll
  for (int j = 0; j < 4; j++){
    int i = base + t*4 + j;
    v[j] = (i < NN) ? cnt[p*NN + i] : 0;
    s += v[j];
  }
  __shared__ int red[256];
  red[t] = s; __syncthreads();
  #pragma unroll
  for (int o = 1; o < 256; o <<= 1){
    int other = (t >= o) ? red[t - o] : 0;
    __syncthreads();
    red[t] += other;
    __syncthreads();
  }
  int ex = red[t] - s + bsums[p*SCB + b];
  #pragma unroll
  for (int j = 0; j < 4; j++){
    int i = base + t*4 + j;
    if (i < NN) start[p*NN + i] = ex;
    ex += v[j];
  }
}

__global__ void csr_fill(const int* __restrict__ twi, const int* __restrict__ start,
                         int* __restrict__ cursor, int* __restrict__ lists){
  int e = blockIdx.x*blockDim.x + threadIdx.x;
  if (e < NE){
    #pragma unroll
    for (int p = 0; p < 3; p++){
      int n = twi[p*NE + e];
      int pos = atomicAdd(&cursor[p*NN + n], 1);
      lists[(size_t)p*NE + start[p*NN + n] + pos] = e;
    }
  }
}

// ------------- gathered GEMM: NP parts per dispatch, small-LDS + NT h stores -----
template<int NP, int DOSCORE>
__launch_bounds__(256)
__global__ void g1k(const unsigned short* __restrict__ xb,
                    const unsigned short* __restrict__ Wcat,
                    const float* __restrict__ W1,
                    const int* __restrict__ twi,
                    unsigned short* __restrict__ h,
                    float* __restrict__ sp,
                    float* __restrict__ stats,
                    int p0){
  __shared__ unsigned short ltu[4][16][128];   // 16 KB bf16 repack
  __shared__ float ssum[128], ssq[128];
  __shared__ float s1s[4], s1q[4];
  const int t = threadIdx.x;
  const int w = t >> 6, lane = t & 63;
  const int lc = lane & 15, kg = lane >> 4;
  const int eBase = blockIdx.x * 64;
  const int edge = eBase + w*16 + lc;
  const int nd0 = twi[edge], nd1 = twi[NE + edge], nd2 = twi[2*NE + edge];
  const unsigned short* ar0 = xb + (size_t)nd0*DD + kg*8;
  const unsigned short* ar1 = xb + (size_t)nd1*DD + kg*8;
  const unsigned short* ar2 = xb + (size_t)nd2*DD + kg*8;

  if (DOSCORE){
    float sa = 0.f;
    #pragma unroll
    for (int ks = 0; ks < 12; ks++){
      const unsigned short* ap = ((ks < 4) ? ar0 : (ks < 8) ? ar1 : ar2) + (ks & 3)*32;
      s16x8 a = *(const s16x8*)ap;
      const float* wp = W1 + ks*32 + kg*8;
      f32x4 w0 = *(const f32x4*)wp;
      f32x4 w1v = *(const f32x4*)(wp + 4);
      #pragma unroll
      for (int j = 0; j < 4; j++) sa += bf2f((unsigned short)a[j])   * w0[j];
      #pragma unroll
      for (int j = 0; j < 4; j++) sa += bf2f((unsigned short)a[4+j]) * w1v[j];
    }
    sa += __shfl_xor(sa, 16);
    sa += __shfl_xor(sa, 32);
    if (lane < 16) sp[edge] = sa;
    float sv = (lane < 16) ? sa : 0.f;
    float qv = sv*sv;
    #pragma unroll
    for (int o = 8; o; o >>= 1){ sv += __shfl_xor(sv, o); qv += __shfl_xor(qv, o); }
    if (lane == 0){ s1s[w] = sv; s1q[w] = qv; }
    __syncthreads();
    if (t == 0){
      atomicAdd(&stats[ST_SUM1], s1s[0]+s1s[1]+s1s[2]+s1s[3]);
      atomicAdd(&stats[ST_SQ1],  s1q[0]+s1q[1]+s1q[2]+s1q[3]);
    }
  }

  #pragma unroll 1
  for (int pp = 0; pp < NP; pp++){
    const int p = p0 + pp;
    if (t < 128){ ssum[t] = 0.f; ssq[t] = 0.f; }
    __syncthreads();

    f32x4 acc[8];
    #pragma unroll
    for (int nf = 0; nf < 8; nf++){ acc[nf][0]=0.f; acc[nf][1]=0.f; acc[nf][2]=0.f; acc[nf][3]=0.f; }

    const unsigned short* wb = Wcat + (size_t)(p*128 + lc)*D3 + kg*8;
    #pragma unroll
    for (int ks = 0; ks < 12; ks++){
      const unsigned short* ap = ((ks < 4) ? ar0 : (ks < 8) ? ar1 : ar2) + (ks & 3)*32;
      s16x8 a = *(const s16x8*)ap;
      #pragma unroll
      for (int nf = 0; nf < 8; nf++){
        s16x8 b = *(const s16x8*)(wb + nf*16*D3 + ks*32);
        acc[nf] = __builtin_amdgcn_mfma_f32_16x16x32_bf16(a, b, acc[nf], 0, 0, 0);
      }
    }

    // ---- col stats from acc via shfl (f32 exact; col=nf*16+lc, rows kg*4+r) ----
    #pragma unroll
    for (int nf = 0; nf < 8; nf++){
      float ps = acc[nf][0]+acc[nf][1]+acc[nf][2]+acc[nf][3];
      float pq = acc[nf][0]*acc[nf][0]+acc[nf][1]*acc[nf][1]
               + acc[nf][2]*acc[nf][2]+acc[nf][3]*acc[nf][3];
      ps += __shfl_xor(ps, 16); ps += __shfl_xor(ps, 32);
      pq += __shfl_xor(pq, 16); pq += __shfl_xor(pq, 32);
      if (lane < 16){
        atomicAdd(&ssum[nf*16 + lc], ps);
        atomicAdd(&ssq [nf*16 + lc], pq);
      }
    }

    // ---- u16 repack (wave-local), nontemporal h stores ----
    #pragma unroll
    for (int nf = 0; nf < 8; nf++)
      #pragma unroll
      for (int r = 0; r < 4; r++)
        ltu[w][kg*4 + r][nf*16 + lc] = f2bf(acc[nf][r]);

    unsigned short* hp = h + (size_t)pp*NE*DD;
    const int rl = lane >> 5, cg = lane & 31;
    #pragma unroll
    for (int it = 0; it < 8; it++){
      const int row = it*2 + rl;
      u16x4 o = *(const u16x4*)&ltu[w][row][cg*4];
      __builtin_nontemporal_store(o, (u16x4*)(hp + (size_t)(eBase + w*16 + row)*DD + cg*4));
    }
    __syncthreads();
    if (t < 128){
      atomicAdd(&stats[ST_SUM + p*128 + t], ssum[t]);
      atomicAdd(&stats[ST_SQ  + p*128 + t], ssq[t]);
    }
  }
}

// ---------------- BN finalize ----------------
__global__ void sfin_score(const float* g1, const float* be1, float* __restrict__ stats){
  if (threadIdx.x == 0){
    float mu = stats[ST_SUM1] / (float)NE;
    float var = stats[ST_SQ1] / (float)NE - mu*mu;
    float sc = g1[0] * rsqrtf(var + EPSBN);
    stats[ST_SCALE1] = sc;
    stats[ST_SHIFT1] = be1[0] - mu*sc;
  }
}

__global__ void sfin_cols(const float* g, const float* be, float* __restrict__ stats, int part){
  int t = threadIdx.x;
  if (t < 128){
    int idx = part*128 + t;
    float mu = stats[ST_SUM + idx] / (float)NE;
    float var = stats[ST_SQ + idx] / (float)NE - mu*mu;
    float sc = g[t] * rsqrtf(var + EPSBN);
    stats[ST_SCALE + idx] = sc;
    stats[ST_SHIFT + idx] = be[t] - mu*sc;
  }
}

__global__ void sfin_all(const float* gT, const float* beT, const float* gM, const float* beM,
                         const float* gB, const float* beB, const float* g1, const float* be1,
                         float* __restrict__ stats){
  int t = threadIdx.x;
  if (t < 384){
    float mu = stats[ST_SUM + t] / (float)NE;
    float var = stats[ST_SQ + t] / (float)NE - mu*mu;
    float g, be;
    if (t < 128)      { g = gT[t];     be = beT[t]; }
    else if (t < 256) { g = gM[t-128]; be = beM[t-128]; }
    else              { g = gB[t-256]; be = beB[t-256]; }
    float sc = g * rsqrtf(var + EPSBN);
    stats[ST_SCALE + t] = sc;
    stats[ST_SHIFT + t] = be - mu*sc;
  } else if (t == 384){
    float mu = stats[ST_SUM1] / (float)NE;
    float var = stats[ST_SQ1] / (float)NE - mu*mu;
    float sc = g1[0] * rsqrtf(var + EPSBN);
    stats[ST_SCALE1] = sc;
    stats[ST_SHIFT1] = be1[0] - mu*sc;
  }
}

// ---------------- softmax: max, sum, att in place ----------------
__global__ void sm_max(float* __restrict__ sp, float* __restrict__ stats){
  const float sc = stats[ST_SCALE1], sh = stats[ST_SHIFT1];
  float lmax = 0.f;
  int stride = gridDim.x*blockDim.x;
  for (int i = blockIdx.x*blockDim.x + threadIdx.x; i < NE; i += stride){
    float s = fmaxf(sp[i]*sc + sh, 0.f);
    sp[i] = s;
    lmax = fmaxf(lmax, s);
  }
  #pragma unroll
  for (int o = 32; o; o >>= 1) lmax = fmaxf(lmax, __shfl_xor(lmax, o));
  __shared__ float red[4];
  if ((threadIdx.x & 63) == 0) red[threadIdx.x >> 6] = lmax;
  __syncthreads();
  if (threadIdx.x == 0){
    float m = fmaxf(fmaxf(red[0], red[1]), fmaxf(red[2], red[3]));
    atomicMax((unsigned int*)&stats[ST_MAX], __float_as_uint(m));
  }
}

__global__ void sm_sum(const float* __restrict__ sp, float* __restrict__ stats){
  const float mx = __uint_as_float(((const unsigned int*)stats)[ST_MAX]);
  float ls = 0.f;
  int stride = gridDim.x*blockDim.x;
  for (int i = blockIdx.x*blockDim.x + threadIdx.x; i < NE; i += stride)
    ls += __expf(sp[i] - mx);
  #pragma unroll
  for (int o = 32; o; o >>= 1) ls += __shfl_xor(ls, o);
  __shared__ float red[4];
  if ((threadIdx.x & 63) == 0) red[threadIdx.x >> 6] = ls;
  __syncthreads();
  if (threadIdx.x == 0)
    atomicAdd(&stats[ST_SEXP], red[0] + red[1] + red[2] + red[3]);
}

__global__ void sm_att(float* __restrict__ sp, const float* __restrict__ stats){
  const float mx = __uint_as_float(((const unsigned int*)stats)[ST_MAX]);
  const float invZ = 1.0f / stats[ST_SEXP];
  int stride = gridDim.x*blockDim.x;
  for (int i = blockIdx.x*blockDim.x + threadIdx.x; i < NE; i += stride)
    sp[i] = __expf(sp[i] - mx) * invZ;
}

// -------- node-centric scatter-mean, NP parts per call, f32 macc += --------
template<int NP>
__launch_bounds__(256)
__global__ void scat(const unsigned short* __restrict__ h,
                     const float* __restrict__ att,
                     const int* __restrict__ cnt, const int* __restrict__ start,
                     const int* __restrict__ lists,
                     const float* __restrict__ stats,
                     float* __restrict__ macc, int p0){
  const int w = threadIdx.x >> 6, lane = threadIdx.x & 63;
  const int n = blockIdx.x*4 + w;
  if (n >= NN) return;
  float a0 = 0.f, a1 = 0.f;
  for (int q = 0; q < NP; q++){
    const int p = p0 + q;
    const unsigned short* hq = h + (size_t)q*NE*DD;
    const float sc0 = stats[ST_SCALE + p*128 + lane];
    const float sh0 = stats[ST_SHIFT + p*128 + lane];
    const float sc1 = stats[ST_SCALE + p*128 + 64 + lane];
    const float sh1 = stats[ST_SHIFT + p*128 + 64 + lane];
    const int cs = start[p*NN + n];
    const int c  = cnt[p*NN + n];
    float p0a = 0.f, p1a = 0.f;
    for (int j = 0; j < c; j++){
      const int e = lists[(size_t)p*NE + cs + j];
      const float av = att[e];
      const float v0 = bf2f(__builtin_nontemporal_load(hq + (size_t)e*DD + lane));
      const float v1 = bf2f(__builtin_nontemporal_load(hq + (size_t)e*DD + 64 + lane));
      p0a += av * fmaxf(v0*sc0 + sh0, 0.f);
      p1a += av * fmaxf(v1*sc1 + sh1, 0.f);
    }
    if (c > 0){ float ic = 1.f / (float)c; a0 += p0a*ic; a1 += p1a*ic; }
  }
  macc[(size_t)n*DD + lane]      += a0;
  macc[(size_t)n*DD + 64 + lane] += a1;
}

// ---------------- zb = bf16(macc @ Wtw^T), fused col stats ----------------
__launch_bounds__(256)
__global__ void g2_gemm(const float* __restrict__ A,
                        const unsigned short* __restrict__ Wtwb,
                        unsigned short* __restrict__ zb,
                        float* __restrict__ stats){
  __shared__ float ssum[128], ssq[128];
  const int t = threadIdx.x;
  const int w = t >> 6, lane = t & 63;
  const int lc = lane & 15, kg = lane >> 4;
  if (t < 128){ ssum[t] = 0.f; ssq[t] = 0.f; }
  const int m0 = blockIdx.x*64 + w*16;
  const int arow = m0 + lc;
  f32x4 acc[8];
  #pragma unroll
  for (int nf = 0; nf < 8; nf++){ acc[nf][0]=0.f; acc[nf][1]=0.f; acc[nf][2]=0.f; acc[nf][3]=0.f; }
  #pragma unroll
  for (int ks = 0; ks < 128; ks += 32){
    s16x8 a;
    if (arow < NN){
      f32x4 a0 = *(const f32x4*)(A + (size_t)arow*DD + ks + kg*8);
      f32x4 a1 = *(const f32x4*)(A + (size_t)arow*DD + ks + kg*8 + 4);
      a[0]=(short)f2bf(a0[0]); a[1]=(short)f2bf(a0[1]); a[2]=(short)f2bf(a0[2]); a[3]=(short)f2bf(a0[3]);
      a[4]=(short)f2bf(a1[0]); a[5]=(short)f2bf(a1[1]); a[6]=(short)f2bf(a1[2]); a[7]=(short)f2bf(a1[3]);
    } else {
      a[0]=0;a[1]=0;a[2]=0;a[3]=0;a[4]=0;a[5]=0;a[6]=0;a[7]=0;
    }
    #pragma unroll
    for (int nf = 0; nf < 8; nf++){
      s16x8 b = *(const s16x8*)(Wtwb + (nf*16 + lc)*DD + ks + kg*8);
      acc[nf] = __builtin_amdgcn_mfma_f32_16x16x32_bf16(a, b, acc[nf], 0, 0, 0);
    }
  }
  float ps[8], pq[8];
  #pragma unroll
  for (int nf = 0; nf < 8; nf++){
    ps[nf] = 0.f; pq[nf] = 0.f;
    const int col = nf*16 + lc;
    #pragma unroll
    for (int r = 0; r < 4; r++){
      int row = m0 + kg*4 + r;
      if (row < NN){
        float v = acc[nf][r];
        zb[(size_t)row*DD + col] = f2bf(v);
        ps[nf] += v; pq[nf] += v*v;
      }
    }
  }
  __syncthreads();
  #pragma unroll
  for (int nf = 0; nf < 8; nf++){
    atomicAdd(&ssum[nf*16 + lc], ps[nf]);
    atomicAdd(&ssq [nf*16 + lc], pq[nf]);
  }
  __syncthreads();
  if (t < 128){
    atomicAdd(&stats[ST_SUM2 + t], ssum[t]);
    atomicAdd(&stats[ST_SQ2  + t], ssq[t]);
  }
}

__global__ void sfin2(const float* gtw, const float* betw, float* __restrict__ stats){
  int c = threadIdx.x;
  if (c < 128){
    float mu = stats[ST_SUM2 + c] / (float)NN;
    float var = stats[ST_SQ2 + c] / (float)NN - mu*mu;
    float sc = gtw[c] * rsqrtf(var + EPSBN);
    stats[ST_SCALE2 + c] = sc;
    stats[ST_SHIFT2 + c] = betw[c] - mu*sc;
  }
}

// ---------------- x += relu(BN(zb)); refresh bf16 copy (vectorized) ----------------
__global__ void fuse_update(const unsigned short* __restrict__ zb,
                            const float* __restrict__ stats,
                            float* __restrict__ xcur, unsigned short* __restrict__ xb){
  const int tot = NN*DD/4;
  int stride = gridDim.x*blockDim.x;
  for (int i = blockIdx.x*blockDim.x + threadIdx.x; i < tot; i += stride){
    u16x4 z4 = ((const u16x4*)zb)[i];
    f32x4 x4 = ((const f32x4*)xcur)[i];
    const int c = (i*4) & 127;
    f32x4 o; u16x4 ob;
    #pragma unroll
    for (int j = 0; j < 4; j++){
      float hv = fmaxf(bf2f(z4[j])*stats[ST_SCALE2 + c + j] + stats[ST_SHIFT2 + c + j], 0.f);
      o[j] = x4[j] + hv;
      ob[j] = f2bf(o[j]);
    }
    ((f32x4*)xcur)[i] = o;
    ((u16x4*)xb)[i] = ob;
  }
}

extern "C" void kernel_launch(void* const* d_in, const int* in_sizes, int n_in,
                              void* d_out, int out_size, void* d_ws, size_t ws_size,
                              hipStream_t stream){
  const float* x    = (const float*)d_in[0];
  const int*   twi  = (const int*)d_in[1];
  const float* W_T  = (const float*)d_in[2];
  const float* W_M  = (const float*)d_in[3];
  const float* W_B  = (const float*)d_in[4];
  const float* W_1  = (const float*)d_in[5];
  const float* W_tw = (const float*)d_in[6];
  const float* g_T  = (const float*)d_in[8];
  const float* be_T = (const float*)d_in[9];
  const float* g_M  = (const float*)d_in[11];
  const float* be_M = (const float*)d_in[12];
  const float* g_B  = (const float*)d_in[14];
  const float* be_B = (const float*)d_in[15];
  const float* g_1  = (const float*)d_in[17];
  const float* be_1 = (const float*)d_in[18];
  const float* g_tw = (const float*)d_in[20];
  const float* be_tw= (const float*)d_in[21];
  float* xcur = (float*)d_out;

  char* ws = (char*)d_ws;
  size_t off = 0;
  auto take = [&](size_t b){ size_t o = off; off += (b + 255) & ~(size_t)255; return o; };
  float* stats = (float*)(ws + take(ST_TOTAL*4));
  unsigned short* Wcat = (unsigned short*)(ws + take(384*384*2));
  unsigned short* Wtwb = (unsigned short*)(ws + take(128*128*2));
  int* bsums  = (int*)(ws + take((size_t)3*SCB*4));
  int* cnt    = (int*)(ws + take((size_t)3*NN*4));
  int* startA = (int*)(ws + take((size_t)3*NN*4));
  int* cursor = (int*)(ws + take((size_t)3*NN*4));
  int* lists  = (int*)(ws + take((size_t)3*NE*4));
  float* sp   = (float*)(ws + take((size_t)NE*4));
  unsigned short* xb = (unsigned short*)(ws + take((size_t)NN*DD*2));
  float* macc = (float*)(ws + take((size_t)NN*DD*4));
  size_t hoff = off;
  unsigned short* h = (unsigned short*)(ws + hoff);
  unsigned short* zb = h;   // alias: zb written only after h fully consumed each layer
  const size_t plane = (size_t)NE*DD*2;
  int P = 0;
  if (ws_size > hoff)
    P = (int)((ws_size - hoff) / plane);
  if (P > 3) P = 3;
  if (P < 1) return;  // cannot run; avoid faulting

  hipMemsetAsync(cnt, 0, (size_t)3*NN*4, stream);
  hipMemsetAsync(cursor, 0, (size_t)3*NN*4, stream);
  init_x<<<1024, 256, 0, stream>>>(x, xcur, xb);
  csr_cnt<<<(NE+255)/256, 256, 0, stream>>>(twi, cnt);
  scan_bs<<<dim3(SCB, 3), 256, 0, stream>>>(cnt, bsums);
  scan_top<<<1, 64, 0, stream>>>(bsums);
  scan_fin<<<dim3(SCB, 3), 256, 0, stream>>>(cnt, bsums, startA);
  csr_fill<<<(NE+255)/256, 256, 0, stream>>>(twi, startA, cursor, lists);

  for (int l = 0; l < KL; l++){
    hipMemsetAsync(stats, 0, ST_TOTAL*4, stream);
    hipMemsetAsync(macc, 0, (size_t)NN*DD*4, stream);
    wprep<<<640, 256, 0, stream>>>(W_T + (size_t)l*DD*D3, W_M + (size_t)l*DD*D3,
                                   W_B + (size_t)l*DD*D3, W_tw + (size_t)l*DD*DD,
                                   Wcat, Wtwb);
    const float* gs[3]  = {g_T  + (size_t)l*DD, g_M  + (size_t)l*DD, g_B  + (size_t)l*DD};
    const float* bes[3] = {be_T + (size_t)l*DD, be_M + (size_t)l*DD, be_B + (size_t)l*DD};
    const float* W1l = W_1 + (size_t)l*D3;

    if (P >= 3){
      g1k<3,1><<<EB, 256, 0, stream>>>(xb, Wcat, W1l, twi, h, sp, stats, 0);
      sfin_all<<<1, 512, 0, stream>>>(gs[0], bes[0], gs[1], bes[1], gs[2], bes[2],
                                      g_1 + l, be_1 + l, stats);
      sm_max<<<1024, 256, 0, stream>>>(sp, stats);
      sm_sum<<<1024, 256, 0, stream>>>(sp, stats);
      sm_att<<<1024, 256, 0, stream>>>(sp, stats);
      scat<3><<<(NN+3)/4, 256, 0, stream>>>(h, sp, cnt, startA, lists, stats, macc, 0);
    } else if (P == 2){
      g1k<2,1><<<EB, 256, 0, stream>>>(xb, Wcat, W1l, twi, h, sp, stats, 0);
      sfin_score<<<1, 64, 0, stream>>>(g_1 + l, be_1 + l, stats);
      sm_max<<<1024, 256, 0, stream>>>(sp, stats);
      sm_sum<<<1024, 256, 0, stream>>>(sp, stats);
      sm_att<<<1024, 256, 0, stream>>>(sp, stats);
      sfin_cols<<<1, 128, 0, stream>>>(gs[0], bes[0], stats, 0);
      sfin_cols<<<1, 128, 0, stream>>>(gs[1], bes[1], stats, 1);
      scat<2><<<(NN+3)/4, 256, 0, stream>>>(h, sp, cnt, startA, lists, stats, macc, 0);
      g1k<1,0><<<EB, 256, 0, stream>>>(xb, Wcat, W1l, twi, h, sp, stats, 2);
      sfin_cols<<<1, 128, 0, stream>>>(gs[2], bes[2], stats, 2);
      scat<1><<<(NN+3)/4, 256, 0, stream>>>(h, sp, cnt, startA, lists, stats, macc, 2);
    } else {
      g1k<1,1><<<EB, 256, 0, stream>>>(xb, Wcat, W1l, twi, h, sp, stats, 0);
      sfin_score<<<1, 64, 0, stream>>>(g_1 + l, be_1 + l, stats);
      sm_max<<<1024, 256, 0, stream>>>(sp, stats);
      sm_sum<<<1024, 256, 0, stream>>>(sp, stats);
      sm_att<<<1024, 256, 0, stream>>>(sp, stats);
      sfin_cols<<<1, 128, 0, stream>>>(gs[0], bes[0], stats, 0);
      scat<1><<<(NN+3)/4, 256, 0, stream>>>(h, sp, cnt, startA, lists, stats, macc, 0);
      for (int p = 1; p < 3; p++){
        g1k<1,0><<<EB, 256, 0, stream>>>(xb, Wcat, W1l, twi, h, sp, stats, p);
        sfin_cols<<<1, 128, 0, stream>>>(gs[p], bes[p], stats, p);
        scat<1><<<(NN+3)/4, 256, 0, stream>>>(h, sp, cnt, startA, lists, stats, macc, p);
      }
    }

    g2_gemm<<<(NN+63)/64, 256, 0, stream>>>(macc, Wtwb, zb, stats);
    sfin2<<<1, 128, 0, stream>>>(g_tw + (size_t)l*DD, be_tw + (size_t)l*DD, stats);
    fuse_update<<<1024, 256, 0, stream>>>(zb, stats, xcur, xb);
  }
}

// Round 8
// 3005.432 us; speedup vs baseline: 1.3978x; 1.0225x over previous
//
#include <hip/hip_runtime.h>

#define NN 100000
#define NE 400000
#define DD 128
#define D3 384
#define KL 2
#define EPSBN 1e-5f
#define EB (NE/64)
#define SCB ((NN + 1023) / 1024)

typedef __attribute__((ext_vector_type(8))) short s16x8;
typedef __attribute__((ext_vector_type(4))) float f32x4;
typedef __attribute__((ext_vector_type(4))) unsigned short u16x4;

#define ST_SUM    0      // [384]
#define ST_SQ     384    // [384]
#define ST_SCALE  768    // [384]
#define ST_SHIFT  1152   // [384]
#define ST_SUM1   1536
#define ST_SQ1    1537
#define ST_MAX    1538
#define ST_SEXP   1539
#define ST_SCALE1 1540
#define ST_SHIFT1 1541
#define ST_SUM2   1542   // [128]
#define ST_SQ2    1670   // [128]
#define ST_SCALE2 1798   // [128]
#define ST_SHIFT2 1926   // [128]
#define ST_TOTAL  2054

__device__ __forceinline__ float bf2f(unsigned short u){
  return __uint_as_float(((unsigned int)u) << 16);
}
__device__ __forceinline__ unsigned short f2bf(float f){
  unsigned int x = __float_as_uint(f);
  x = x + 0x7FFFu + ((x >> 16) & 1u);
  return (unsigned short)(x >> 16);
}

// ---------------- init: x -> xcur (f32) + xb (bf16), vectorized ----------------
__global__ void init_x(const float* __restrict__ x, float* __restrict__ xcur,
                       unsigned short* __restrict__ xb){
  const int tot = NN*DD/4;
  int stride = gridDim.x * blockDim.x;
  for (int i = blockIdx.x*blockDim.x + threadIdx.x; i < tot; i += stride){
    f32x4 v = ((const f32x4*)x)[i];
    ((f32x4*)xcur)[i] = v;
    u16x4 o; o[0]=f2bf(v[0]); o[1]=f2bf(v[1]); o[2]=f2bf(v[2]); o[3]=f2bf(v[3]);
    ((u16x4*)xb)[i] = o;
  }
}

// ---------------- weight prep (per layer) ----------------
__global__ void wprep(const float* __restrict__ WT, const float* __restrict__ WM,
                      const float* __restrict__ WB, const float* __restrict__ Wtw,
                      unsigned short* __restrict__ Wcat, unsigned short* __restrict__ Wtwb){
  int stride = gridDim.x * blockDim.x;
  int tid = blockIdx.x*blockDim.x + threadIdx.x;
  for (int i = tid; i < 384*384; i += stride){
    int n = i / 384, k = i - n*384;
    float v;
    if (n < 128)      v = WT[n*384 + k];
    else if (n < 256) v = WM[(n-128)*384 + k];
    else              v = WB[(n-256)*384 + k];
    Wcat[i] = f2bf(v);
  }
  for (int i = tid; i < 128*128; i += stride) Wtwb[i] = f2bf(Wtw[i]);
}

// ---------------- CSR build ----------------
__global__ void csr_cnt(const int* __restrict__ twi, int* __restrict__ cnt){
  int e = blockIdx.x*blockDim.x + threadIdx.x;
  if (e < NE){
    atomicAdd(&cnt[0*NN + twi[0*NE + e]], 1);
    atomicAdd(&cnt[1*NN + twi[1*NE + e]], 1);
    atomicAdd(&cnt[2*NN + twi[2*NE + e]], 1);
  }
}

__global__ void scan_bs(const int* __restrict__ cnt, int* __restrict__ bsums){
  const int p = blockIdx.y, b = blockIdx.x, t = threadIdx.x;
  const int base = b * 1024;
  int s = 0;
  #pragma unroll
  for (int j = 0; j < 4; j++){
    int i = base + t + j*256;
    if (i < NN) s += cnt[p*NN + i];
  }
  __shared__ int red[256];
  red[t] = s; __syncthreads();
  #pragma unroll
  for (int o = 128; o; o >>= 1){
    if (t < o) red[t] += red[t+o];
    __syncthreads();
  }
  if (t == 0) bsums[p*SCB + b] = red[0];
}

__global__ void scan_top(int* __restrict__ bsums){
  const int p = threadIdx.x;
  if (p < 3){
    int run = 0;
    for (int i = 0; i < SCB; i++){ int v = bsums[p*SCB + i]; bsums[p*SCB + i] = run; run += v; }
  }
}

__global__ void scan_fin(const int* __restrict__ cnt, const int* __restrict__ bsums,
                         int* __restrict__ start){
  const int p = blockIdx.y, b = blockIdx.x, t = threadIdx.x;
  const int base = b * 1024;
  int v[4]; int s = 0;
  #pragma unroll
  for (int j = 0; j < 4; j++){
    int i = base + t*4 + j;
    v[j] = (i < NN) ? cnt[p*NN + i] : 0;
    s += v[j];
  }
  __shared__ int red[256];
  red[t] = s; __syncthreads();
  #pragma unroll
  for (int o = 1; o < 256; o <<= 1){
    int other = (t >= o) ? red[t - o] : 0;
    __syncthreads();
    red[t] += other;
    __syncthreads();
  }
  int ex = red[t] - s + bsums[p*SCB + b];
  #pragma unroll
  for (int j = 0; j < 4; j++){
    int i = base + t*4 + j;
    if (i < NN) start[p*NN + i] = ex;
    ex += v[j];
  }
}

__global__ void csr_fill(const int* __restrict__ twi, const int* __restrict__ start,
                         int* __restrict__ cursor, int* __restrict__ lists){
  int e = blockIdx.x*blockDim.x + threadIdx.x;
  if (e < NE){
    #pragma unroll
    for (int p = 0; p < 3; p++){
      int n = twi[p*NE + e];
      int pos = atomicAdd(&cursor[p*NN + n], 1);
      lists[(size_t)p*NE + start[p*NN + n] + pos] = e;
    }
  }
}

// ------------- gathered GEMM: NP parts per dispatch, pinned A-prefetch -----------
template<int NP, int DOSCORE>
__launch_bounds__(256)
__global__ void g1k(const unsigned short* __restrict__ xb,
                    const unsigned short* __restrict__ Wcat,
                    const float* __restrict__ W1,
                    const int* __restrict__ twi,
                    unsigned short* __restrict__ h,
                    float* __restrict__ sp,
                    float* __restrict__ stats,
                    int p0){
  __shared__ unsigned short ltu[4][16][128];   // 16 KB bf16 repack
  __shared__ float ssum[128], ssq[128];
  __shared__ float s1s[4], s1q[4];
  const int t = threadIdx.x;
  const int w = t >> 6, lane = t & 63;
  const int lc = lane & 15, kg = lane >> 4;
  const int eBase = blockIdx.x * 64;
  const int edge = eBase + w*16 + lc;
  const int nd0 = twi[edge], nd1 = twi[NE + edge], nd2 = twi[2*NE + edge];

  // ---- issue ALL 12 A-gathers back-to-back; opaque asm pins them (no remat/sink) ----
  s16x8 areg[12];
  #pragma unroll
  for (int ks = 0; ks < 12; ks++){
    const int nd = (ks < 4) ? nd0 : ((ks < 8) ? nd1 : nd2);
    areg[ks] = *(const s16x8*)(xb + (size_t)nd*DD + (ks & 3)*32 + kg*8);
  }
  asm volatile(""
    : "+v"(areg[0]), "+v"(areg[1]), "+v"(areg[2]),  "+v"(areg[3]),
      "+v"(areg[4]), "+v"(areg[5]), "+v"(areg[6]),  "+v"(areg[7]),
      "+v"(areg[8]), "+v"(areg[9]), "+v"(areg[10]), "+v"(areg[11]));

  if (DOSCORE){
    float sa = 0.f;
    #pragma unroll
    for (int ks = 0; ks < 12; ks++){
      const float* wp = W1 + ks*32 + kg*8;
      f32x4 w0 = *(const f32x4*)wp;
      f32x4 w1v = *(const f32x4*)(wp + 4);
      #pragma unroll
      for (int j = 0; j < 4; j++) sa += bf2f((unsigned short)areg[ks][j])   * w0[j];
      #pragma unroll
      for (int j = 0; j < 4; j++) sa += bf2f((unsigned short)areg[ks][4+j]) * w1v[j];
    }
    sa += __shfl_xor(sa, 16);
    sa += __shfl_xor(sa, 32);
    if (lane < 16) sp[edge] = sa;
    float sv = (lane < 16) ? sa : 0.f;
    float qv = sv*sv;
    #pragma unroll
    for (int o = 8; o; o >>= 1){ sv += __shfl_xor(sv, o); qv += __shfl_xor(qv, o); }
    if (lane == 0){ s1s[w] = sv; s1q[w] = qv; }
    __syncthreads();
    if (t == 0){
      atomicAdd(&stats[ST_SUM1], s1s[0]+s1s[1]+s1s[2]+s1s[3]);
      atomicAdd(&stats[ST_SQ1],  s1q[0]+s1q[1]+s1q[2]+s1q[3]);
    }
  }

  #pragma unroll 1
  for (int pp = 0; pp < NP; pp++){
    const int p = p0 + pp;
    if (t < 128){ ssum[t] = 0.f; ssq[t] = 0.f; }
    __syncthreads();

    f32x4 acc[8];
    #pragma unroll
    for (int nf = 0; nf < 8; nf++){ acc[nf][0]=0.f; acc[nf][1]=0.f; acc[nf][2]=0.f; acc[nf][3]=0.f; }

    const unsigned short* wb = Wcat + (size_t)(p*128 + lc)*D3 + kg*8;
    #pragma unroll
    for (int ks = 0; ks < 12; ks++){
      #pragma unroll
      for (int nf = 0; nf < 8; nf++){
        s16x8 b = *(const s16x8*)(wb + nf*16*D3 + ks*32);
        acc[nf] = __builtin_amdgcn_mfma_f32_16x16x32_bf16(areg[ks], b, acc[nf], 0, 0, 0);
      }
    }

    // ---- col stats from acc via shfl (f32 exact; col=nf*16+lc, rows kg*4+r) ----
    #pragma unroll
    for (int nf = 0; nf < 8; nf++){
      float ps = acc[nf][0]+acc[nf][1]+acc[nf][2]+acc[nf][3];
      float pq = acc[nf][0]*acc[nf][0]+acc[nf][1]*acc[nf][1]
               + acc[nf][2]*acc[nf][2]+acc[nf][3]*acc[nf][3];
      ps += __shfl_xor(ps, 16); ps += __shfl_xor(ps, 32);
      pq += __shfl_xor(pq, 16); pq += __shfl_xor(pq, 32);
      if (lane < 16){
        atomicAdd(&ssum[nf*16 + lc], ps);
        atomicAdd(&ssq [nf*16 + lc], pq);
      }
    }

    // ---- u16 repack (wave-local), nontemporal h stores ----
    #pragma unroll
    for (int nf = 0; nf < 8; nf++)
      #pragma unroll
      for (int r = 0; r < 4; r++)
        ltu[w][kg*4 + r][nf*16 + lc] = f2bf(acc[nf][r]);

    unsigned short* hp = h + (size_t)pp*NE*DD;
    const int rl = lane >> 5, cg = lane & 31;
    #pragma unroll
    for (int it = 0; it < 8; it++){
      const int row = it*2 + rl;
      u16x4 o = *(const u16x4*)&ltu[w][row][cg*4];
      __builtin_nontemporal_store(o, (u16x4*)(hp + (size_t)(eBase + w*16 + row)*DD + cg*4));
    }
    __syncthreads();
    if (t < 128){
      atomicAdd(&stats[ST_SUM + p*128 + t], ssum[t]);
      atomicAdd(&stats[ST_SQ  + p*128 + t], ssq[t]);
    }
  }
}

// ---------------- BN finalize ----------------
__global__ void sfin_score(const float* g1, const float* be1, float* __restrict__ stats){
  if (threadIdx.x == 0){
    float mu = stats[ST_SUM1] / (float)NE;
    float var = stats[ST_SQ1] / (float)NE - mu*mu;
    float sc = g1[0] * rsqrtf(var + EPSBN);
    stats[ST_SCALE1] = sc;
    stats[ST_SHIFT1] = be1[0] - mu*sc;
  }
}

__global__ void sfin_cols(const float* g, const float* be, float* __restrict__ stats, int part){
  int t = threadIdx.x;
  if (t < 128){
    int idx = part*128 + t;
    float mu = stats[ST_SUM + idx] / (float)NE;
    float var = stats[ST_SQ + idx] / (float)NE - mu*mu;
    float sc = g[t] * rsqrtf(var + EPSBN);
    stats[ST_SCALE + idx] = sc;
    stats[ST_SHIFT + idx] = be[t] - mu*sc;
  }
}

__global__ void sfin_all(const float* gT, const float* beT, const float* gM, const float* beM,
                         const float* gB, const float* beB, const float* g1, const float* be1,
                         float* __restrict__ stats){
  int t = threadIdx.x;
  if (t < 384){
    float mu = stats[ST_SUM + t] / (float)NE;
    float var = stats[ST_SQ + t] / (float)NE - mu*mu;
    float g, be;
    if (t < 128)      { g = gT[t];     be = beT[t]; }
    else if (t < 256) { g = gM[t-128]; be = beM[t-128]; }
    else              { g = gB[t-256]; be = beB[t-256]; }
    float sc = g * rsqrtf(var + EPSBN);
    stats[ST_SCALE + t] = sc;
    stats[ST_SHIFT + t] = be - mu*sc;
  } else if (t == 384){
    float mu = stats[ST_SUM1] / (float)NE;
    float var = stats[ST_SQ1] / (float)NE - mu*mu;
    float sc = g1[0] * rsqrtf(var + EPSBN);
    stats[ST_SCALE1] = sc;
    stats[ST_SHIFT1] = be1[0] - mu*sc;
  }
}

// ---------------- softmax: max, sum, att in place ----------------
__global__ void sm_max(float* __restrict__ sp, float* __restrict__ stats){
  const float sc = stats[ST_SCALE1], sh = stats[ST_SHIFT1];
  float lmax = 0.f;
  int stride = gridDim.x*blockDim.x;
  for (int i = blockIdx.x*blockDim.x + threadIdx.x; i < NE; i += stride){
    float s = fmaxf(sp[i]*sc + sh, 0.f);
    sp[i] = s;
    lmax = fmaxf(lmax, s);
  }
  #pragma unroll
  for (int o = 32; o; o >>= 1) lmax = fmaxf(lmax, __shfl_xor(lmax, o));
  __shared__ float red[4];
  if ((threadIdx.x & 63) == 0) red[threadIdx.x >> 6] = lmax;
  __syncthreads();
  if (threadIdx.x == 0){
    float m = fmaxf(fmaxf(red[0], red[1]), fmaxf(red[2], red[3]));
    atomicMax((unsigned int*)&stats[ST_MAX], __float_as_uint(m));
  }
}

__global__ void sm_sum(const float* __restrict__ sp, float* __restrict__ stats){
  const float mx = __uint_as_float(((const unsigned int*)stats)[ST_MAX]);
  float ls = 0.f;
  int stride = gridDim.x*blockDim.x;
  for (int i = blockIdx.x*blockDim.x + threadIdx.x; i < NE; i += stride)
    ls += __expf(sp[i] - mx);
  #pragma unroll
  for (int o = 32; o; o >>= 1) ls += __shfl_xor(ls, o);
  __shared__ float red[4];
  if ((threadIdx.x & 63) == 0) red[threadIdx.x >> 6] = ls;
  __syncthreads();
  if (threadIdx.x == 0)
    atomicAdd(&stats[ST_SEXP], red[0] + red[1] + red[2] + red[3]);
}

__global__ void sm_att(float* __restrict__ sp, const float* __restrict__ stats){
  const float mx = __uint_as_float(((const unsigned int*)stats)[ST_MAX]);
  const float invZ = 1.0f / stats[ST_SEXP];
  int stride = gridDim.x*blockDim.x;
  for (int i = blockIdx.x*blockDim.x + threadIdx.x; i < NE; i += stride)
    sp[i] = __expf(sp[i] - mx) * invZ;
}

// -------- node-centric scatter-mean, NP parts per call, f32 macc += --------
template<int NP>
__launch_bounds__(256)
__global__ void scat(const unsigned short* __restrict__ h,
                     const float* __restrict__ att,
                     const int* __restrict__ cnt, const int* __restrict__ start,
                     const int* __restrict__ lists,
                     const float* __restrict__ stats,
                     float* __restrict__ macc, int p0){
  const int w = threadIdx.x >> 6, lane = threadIdx.x & 63;
  const int n = blockIdx.x*4 + w;
  if (n >= NN) return;
  float a0 = 0.f, a1 = 0.f;
  for (int q = 0; q < NP; q++){
    const int p = p0 + q;
    const unsigned short* hq = h + (size_t)q*NE*DD;
    const float sc0 = stats[ST_SCALE + p*128 + lane];
    const float sh0 = stats[ST_SHIFT + p*128 + lane];
    const float sc1 = stats[ST_SCALE + p*128 + 64 + lane];
    const float sh1 = stats[ST_SHIFT + p*128 + 64 + lane];
    const int cs = start[p*NN + n];
    const int c  = cnt[p*NN + n];
    float p0a = 0.f, p1a = 0.f;
    for (int j = 0; j < c; j++){
      const int e = lists[(size_t)p*NE + cs + j];
      const float av = att[e];
      const float v0 = bf2f(__builtin_nontemporal_load(hq + (size_t)e*DD + lane));
      const float v1 = bf2f(__builtin_nontemporal_load(hq + (size_t)e*DD + 64 + lane));
      p0a += av * fmaxf(v0*sc0 + sh0, 0.f);
      p1a += av * fmaxf(v1*sc1 + sh1, 0.f);
    }
    if (c > 0){ float ic = 1.f / (float)c; a0 += p0a*ic; a1 += p1a*ic; }
  }
  macc[(size_t)n*DD + lane]      += a0;
  macc[(size_t)n*DD + 64 + lane] += a1;
}

// ---------------- zb = bf16(macc @ Wtw^T), fused col stats ----------------
__launch_bounds__(256)
__global__ void g2_gemm(const float* __restrict__ A,
                        const unsigned short* __restrict__ Wtwb,
                        unsigned short* __restrict__ zb,
                        float* __restrict__ stats){
  __shared__ float ssum[128], ssq[128];
  const int t = threadIdx.x;
  const int w = t >> 6, lane = t & 63;
  const int lc = lane & 15, kg = lane >> 4;
  if (t < 128){ ssum[t] = 0.f; ssq[t] = 0.f; }
  const int m0 = blockIdx.x*64 + w*16;
  const int arow = m0 + lc;
  f32x4 acc[8];
  #pragma unroll
  for (int nf = 0; nf < 8; nf++){ acc[nf][0]=0.f; acc[nf][1]=0.f; acc[nf][2]=0.f; acc[nf][3]=0.f; }
  #pragma unroll
  for (int ks = 0; ks < 128; ks += 32){
    s16x8 a;
    if (arow < NN){
      f32x4 a0 = *(const f32x4*)(A + (size_t)arow*DD + ks + kg*8);
      f32x4 a1 = *(const f32x4*)(A + (size_t)arow*DD + ks + kg*8 + 4);
      a[0]=(short)f2bf(a0[0]); a[1]=(short)f2bf(a0[1]); a[2]=(short)f2bf(a0[2]); a[3]=(short)f2bf(a0[3]);
      a[4]=(short)f2bf(a1[0]); a[5]=(short)f2bf(a1[1]); a[6]=(short)f2bf(a1[2]); a[7]=(short)f2bf(a1[3]);
    } else {
      a[0]=0;a[1]=0;a[2]=0;a[3]=0;a[4]=0;a[5]=0;a[6]=0;a[7]=0;
    }
    #pragma unroll
    for (int nf = 0; nf < 8; nf++){
      s16x8 b = *(const s16x8*)(Wtwb + (nf*16 + lc)*DD + ks + kg*8);
      acc[nf] = __builtin_amdgcn_mfma_f32_16x16x32_bf16(a, b, acc[nf], 0, 0, 0);
    }
  }
  float ps[8], pq[8];
  #pragma unroll
  for (int nf = 0; nf < 8; nf++){
    ps[nf] = 0.f; pq[nf] = 0.f;
    const int col = nf*16 + lc;
    #pragma unroll
    for (int r = 0; r < 4; r++){
      int row = m0 + kg*4 + r;
      if (row < NN){
        float v = acc[nf][r];
        zb[(size_t)row*DD + col] = f2bf(v);
        ps[nf] += v; pq[nf] += v*v;
      }
    }
  }
  __syncthreads();
  #pragma unroll
  for (int nf = 0; nf < 8; nf++){
    atomicAdd(&ssum[nf*16 + lc], ps[nf]);
    atomicAdd(&ssq [nf*16 + lc], pq[nf]);
  }
  __syncthreads();
  if (t < 128){
    atomicAdd(&stats[ST_SUM2 + t], ssum[t]);
    atomicAdd(&stats[ST_SQ2  + t], ssq[t]);
  }
}

__global__ void sfin2(const float* gtw, const float* betw, float* __restrict__ stats){
  int c = threadIdx.x;
  if (c < 128){
    float mu = stats[ST_SUM2 + c] / (float)NN;
    float var = stats[ST_SQ2 + c] / (float)NN - mu*mu;
    float sc = gtw[c] * rsqrtf(var + EPSBN);
    stats[ST_SCALE2 + c] = sc;
    stats[ST_SHIFT2 + c] = betw[c] - mu*sc;
  }
}

// ---------------- x += relu(BN(zb)); refresh bf16 copy (vectorized) ----------------
__global__ void fuse_update(const unsigned short* __restrict__ zb,
                            const float* __restrict__ stats,
                            float* __restrict__ xcur, unsigned short* __restrict__ xb){
  const int tot = NN*DD/4;
  int stride = gridDim.x*blockDim.x;
  for (int i = blockIdx.x*blockDim.x + threadIdx.x; i < tot; i += stride){
    u16x4 z4 = ((const u16x4*)zb)[i];
    f32x4 x4 = ((const f32x4*)xcur)[i];
    const int c = (i*4) & 127;
    f32x4 o; u16x4 ob;
    #pragma unroll
    for (int j = 0; j < 4; j++){
      float hv = fmaxf(bf2f(z4[j])*stats[ST_SCALE2 + c + j] + stats[ST_SHIFT2 + c + j], 0.f);
      o[j] = x4[j] + hv;
      ob[j] = f2bf(o[j]);
    }
    ((f32x4*)xcur)[i] = o;
    ((u16x4*)xb)[i] = ob;
  }
}

extern "C" void kernel_launch(void* const* d_in, const int* in_sizes, int n_in,
                              void* d_out, int out_size, void* d_ws, size_t ws_size,
                              hipStream_t stream){
  const float* x    = (const float*)d_in[0];
  const int*   twi  = (const int*)d_in[1];
  const float* W_T  = (const float*)d_in[2];
  const float* W_M  = (const float*)d_in[3];
  const float* W_B  = (const float*)d_in[4];
  const float* W_1  = (const float*)d_in[5];
  const float* W_tw = (const float*)d_in[6];
  const float* g_T  = (const float*)d_in[8];
  const float* be_T = (const float*)d_in[9];
  const float* g_M  = (const float*)d_in[11];
  const float* be_M = (const float*)d_in[12];
  const float* g_B  = (const float*)d_in[14];
  const float* be_B = (const float*)d_in[15];
  const float* g_1  = (const float*)d_in[17];
  const float* be_1 = (const float*)d_in[18];
  const float* g_tw = (const float*)d_in[20];
  const float* be_tw= (const float*)d_in[21];
  float* xcur = (float*)d_out;

  char* ws = (char*)d_ws;
  size_t off = 0;
  auto take = [&](size_t b){ size_t o = off; off += (b + 255) & ~(size_t)255; return o; };
  float* stats = (float*)(ws + take(ST_TOTAL*4));
  unsigned short* Wcat = (unsigned short*)(ws + take(384*384*2));
  unsigned short* Wtwb = (unsigned short*)(ws + take(128*128*2));
  int* bsums  = (int*)(ws + take((size_t)3*SCB*4));
  int* cnt    = (int*)(ws + take((size_t)3*NN*4));
  int* startA = (int*)(ws + take((size_t)3*NN*4));
  int* cursor = (int*)(ws + take((size_t)3*NN*4));
  int* lists  = (int*)(ws + take((size_t)3*NE*4));
  float* sp   = (float*)(ws + take((size_t)NE*4));
  unsigned short* xb = (unsigned short*)(ws + take((size_t)NN*DD*2));
  float* macc = (float*)(ws + take((size_t)NN*DD*4));
  size_t hoff = off;
  unsigned short* h = (unsigned short*)(ws + hoff);
  unsigned short* zb = h;   // alias: zb written only after h fully consumed each layer
  const size_t plane = (size_t)NE*DD*2;
  int P = 0;
  if (ws_size > hoff)
    P = (int)((ws_size - hoff) / plane);
  if (P > 3) P = 3;
  if (P < 1) return;  // cannot run; avoid faulting

  hipMemsetAsync(cnt, 0, (size_t)3*NN*4, stream);
  hipMemsetAsync(cursor, 0, (size_t)3*NN*4, stream);
  init_x<<<1024, 256, 0, stream>>>(x, xcur, xb);
  csr_cnt<<<(NE+255)/256, 256, 0, stream>>>(twi, cnt);
  scan_bs<<<dim3(SCB, 3), 256, 0, stream>>>(cnt, bsums);
  scan_top<<<1, 64, 0, stream>>>(bsums);
  scan_fin<<<dim3(SCB, 3), 256, 0, stream>>>(cnt, bsums, startA);
  csr_fill<<<(NE+255)/256, 256, 0, stream>>>(twi, startA, cursor, lists);

  for (int l = 0; l < KL; l++){
    hipMemsetAsync(stats, 0, ST_TOTAL*4, stream);
    hipMemsetAsync(macc, 0, (size_t)NN*DD*4, stream);
    wprep<<<640, 256, 0, stream>>>(W_T + (size_t)l*DD*D3, W_M + (size_t)l*DD*D3,
                                   W_B + (size_t)l*DD*D3, W_tw + (size_t)l*DD*DD,
                                   Wcat, Wtwb);
    const float* gs[3]  = {g_T  + (size_t)l*DD, g_M  + (size_t)l*DD, g_B  + (size_t)l*DD};
    const float* bes[3] = {be_T + (size_t)l*DD, be_M + (size_t)l*DD, be_B + (size_t)l*DD};
    const float* W1l = W_1 + (size_t)l*D3;

    if (P >= 3){
      g1k<3,1><<<EB, 256, 0, stream>>>(xb, Wcat, W1l, twi, h, sp, stats, 0);
      sfin_all<<<1, 512, 0, stream>>>(gs[0], bes[0], gs[1], bes[1], gs[2], bes[2],
                                      g_1 + l, be_1 + l, stats);
      sm_max<<<1024, 256, 0, stream>>>(sp, stats);
      sm_sum<<<1024, 256, 0, stream>>>(sp, stats);
      sm_att<<<1024, 256, 0, stream>>>(sp, stats);
      scat<3><<<(NN+3)/4, 256, 0, stream>>>(h, sp, cnt, startA, lists, stats, macc, 0);
    } else if (P == 2){
      g1k<2,1><<<EB, 256, 0, stream>>>(xb, Wcat, W1l, twi, h, sp, stats, 0);
      sfin_score<<<1, 64, 0, stream>>>(g_1 + l, be_1 + l, stats);
      sm_max<<<1024, 256, 0, stream>>>(sp, stats);
      sm_sum<<<1024, 256, 0, stream>>>(sp, stats);
      sm_att<<<1024, 256, 0, stream>>>(sp, stats);
      sfin_cols<<<1, 128, 0, stream>>>(gs[0], bes[0], stats, 0);
      sfin_cols<<<1, 128, 0, stream>>>(gs[1], bes[1], stats, 1);
      scat<2><<<(NN+3)/4, 256, 0, stream>>>(h, sp, cnt, startA, lists, stats, macc, 0);
      g1k<1,0><<<EB, 256, 0, stream>>>(xb, Wcat, W1l, twi, h, sp, stats, 2);
      sfin_cols<<<1, 128, 0, stream>>>(gs[2], bes[2], stats, 2);
      scat<1><<<(NN+3)/4, 256, 0, stream>>>(h, sp, cnt, startA, lists, stats, macc, 2);
    } else {
      g1k<1,1><<<EB, 256, 0, stream>>>(xb, Wcat, W1l, twi, h, sp, stats, 0);
      sfin_score<<<1, 64, 0, stream>>>(g_1 + l, be_1 + l, stats);
      sm_max<<<1024, 256, 0, stream>>>(sp, stats);
      sm_sum<<<1024, 256, 0, stream>>>(sp, stats);
      sm_att<<<1024, 256, 0, stream>>>(sp, stats);
      sfin_cols<<<1, 128, 0, stream>>>(gs[0], bes[0], stats, 0);
      scat<1><<<(NN+3)/4, 256, 0, stream>>>(h, sp, cnt, startA, lists, stats, macc, 0);
      for (int p = 1; p < 3; p++){
        g1k<1,0><<<EB, 256, 0, stream>>>(xb, Wcat, W1l, twi, h, sp, stats, p);
        sfin_cols<<<1, 128, 0, stream>>>(gs[p], bes[p], stats, p);
        scat<1><<<(NN+3)/4, 256, 0, stream>>>(h, sp, cnt, startA, lists, stats, macc, p);
      }
    }

    g2_gemm<<<(NN+63)/64, 256, 0, stream>>>(macc, Wtwb, zb, stats);
    sfin2<<<1, 128, 0, stream>>>(g_tw + (size_t)l*DD, be_tw + (size_t)l*DD, stats);
    fuse_update<<<1024, 256, 0, stream>>>(zb, stats, xcur, xb);
  }
}